// Round 11
// baseline (597.481 us; speedup 1.0000x reference)
//
#include <hip/hip_runtime.h>
#include <hip/hip_fp16.h>
#include <math.h>

#define NN 100000
#define NE 1600000
#define NB 256
#define NEGF (-1e30f)
#define NSCAN_BLK ((NN + 1023) / 1024)
#define GVB 1024            // grid-stride GEMV blocks
#define P_SORT 256          // blocks in coarse histogram/scatter
#define NBKT 391            // ceil(NN/256) coarse buckets (dst>>8)
#define HLEN (NBKT * P_SORT)
#define HSCAN_BLK ((HLEN + 1023) / 1024)
#define BKT_CAP 6144        // LDS staging ints (24 KB); avg bucket = 4096 edges

// ---------------- graph offsets via binary search (batch is sorted) ----------------
__global__ void k_offs_bs(const int* __restrict__ batch, int* __restrict__ offs) {
    int g = blockIdx.x * 256 + threadIdx.x;
    if (g > NB) return;
    int lo = 0, hi = NN;
    while (lo < hi) { int mid = (lo + hi) >> 1; if (batch[mid] < g) lo = mid + 1; else hi = mid; }
    offs[g] = lo;
}

// ---------------- CSR build: two-level counting sort ----------------
__global__ void k_hist_coarse(const int* __restrict__ dst, int* __restrict__ H) {
    __shared__ int lh[NBKT];
    int p = blockIdx.x, tid = threadIdx.x;
    for (int i = tid; i < NBKT; i += 256) lh[i] = 0;
    __syncthreads();
    int c0 = p * (NE / P_SORT), c1 = c0 + NE / P_SORT;
    for (int i = c0 + tid; i < c1; i += 256) atomicAdd(&lh[dst[i] >> 8], 1);
    __syncthreads();
    for (int i = tid; i < NBKT; i += 256) H[i * P_SORT + p] = lh[i];
}
__global__ void k_iscan_blk(const int* __restrict__ in, int* __restrict__ pref,
                            int* __restrict__ bsums, int len) {
    int blk = blockIdx.x, tid = threadIdx.x;
    int base = blk * 1024;
    int vals[4], tsum = 0;
    for (int j = 0; j < 4; ++j) {
        int idx = base + tid * 4 + j;
        int v = (idx < len) ? in[idx] : 0;
        vals[j] = tsum; tsum += v;               // exclusive within thread
    }
    __shared__ int sh[256];
    sh[tid] = tsum; __syncthreads();
    for (int o = 1; o < 256; o <<= 1) {
        int v = (tid >= o) ? sh[tid - o] : 0;
        __syncthreads();
        sh[tid] += v;
        __syncthreads();
    }
    int excl = sh[tid] - tsum;
    for (int j = 0; j < 4; ++j) {
        int idx = base + tid * 4 + j;
        if (idx < len) pref[idx] = excl + vals[j];
    }
    if (tid == 255) bsums[blk] = sh[255];
}
__global__ void k_iscan_mid(int* __restrict__ bsums, int nb) {
    int acc = 0;
    for (int i = 0; i < nb; ++i) { int v = bsums[i]; bsums[i] = acc; acc += v; }
}
__global__ void k_iscan_add(int* __restrict__ pref, const int* __restrict__ bsums, int len) {
    int idx = blockIdx.x * 256 + threadIdx.x;
    if (idx < len) pref[idx] += bsums[idx >> 10];
}
__global__ void k_scatter_pairs(const int* __restrict__ src, const int* __restrict__ dst,
                                const int* __restrict__ Hs, int2* __restrict__ ebuf) {
    __shared__ int curs[NBKT];
    int p = blockIdx.x, tid = threadIdx.x;
    for (int i = tid; i < NBKT; i += 256) curs[i] = Hs[i * P_SORT + p];
    __syncthreads();
    int c0 = p * (NE / P_SORT), c1 = c0 + NE / P_SORT;
    for (int i = c0 + tid; i < c1; i += 256) {
        int d = dst[i];
        int pos = atomicAdd(&curs[d >> 8], 1);
        ebuf[pos] = make_int2(src[i], d);
    }
}
__global__ void k_bucket_csr(const int2* __restrict__ ebuf, const int* __restrict__ Hs,
                             int* __restrict__ roffs, int* __restrict__ csrc) {
    __shared__ int hist2[256];
    __shared__ int curs2[256];
    __shared__ int sh[256];
    __shared__ int stage[BKT_CAP];
    int b = blockIdx.x, tid = threadIdx.x;
    int e0 = Hs[b * P_SORT];
    int e1 = (b + 1 < NBKT) ? Hs[(b + 1) * P_SORT] : NE;
    int n0 = b * 256;
    int cntb = e1 - e0;
    if (b == 0 && tid == 0) roffs[NN] = NE;
    hist2[tid] = 0;
    __syncthreads();
    for (int i = e0 + tid; i < e1; i += 256) atomicAdd(&hist2[ebuf[i].y & 255], 1);
    __syncthreads();
    int v = hist2[tid];
    sh[tid] = v; __syncthreads();
    for (int o = 1; o < 256; o <<= 1) {
        int u = (tid >= o) ? sh[tid - o] : 0;
        __syncthreads();
        sh[tid] += u;
        __syncthreads();
    }
    int excl = sh[tid] - v;
    int node = n0 + tid;
    if (node < NN) roffs[node] = e0 + excl;
    curs2[tid] = excl;
    __syncthreads();
    if (cntb <= BKT_CAP) {
        for (int i = e0 + tid; i < e1; i += 256) {
            int2 pr = ebuf[i];
            int pos = atomicAdd(&curs2[pr.y & 255], 1);
            stage[pos] = pr.x;
        }
        __syncthreads();
        for (int i = tid; i < cntb; i += 256) csrc[e0 + i] = stage[i];
    } else {
        for (int i = e0 + tid; i < e1; i += 256) {
            int2 pr = ebuf[i];
            int pos = atomicAdd(&curs2[pr.y & 255], 1);
            csrc[e0 + pos] = pr.x;
        }
    }
}

// ---------------- GEMV kernels: W column in VGPRs, uniform-address broadcast loads ---------
// pre1: y = x @ W11 (K=128, R=4). Broadcast operand loaded at wave-uniform address
// (readfirstlane-pinned row base) -> scalar-pipe eligible, no readlane on VALU.
__global__ __launch_bounds__(256, 1) void k_pre1_g(const float* __restrict__ x,
                                                   const float* __restrict__ W,
                                                   float* __restrict__ y) {
    int tid = threadIdx.x, w = tid >> 6, l = tid & 63;
    float Wc[128];
#pragma unroll
    for (int k = 0; k < 128; ++k) Wc[k] = W[k * 64 + l];
    int g = blockIdx.x * 4 + w;
    const int G = GVB * 4;
    for (int t = g; t < NN / 4; t += G) {
        int n0 = __builtin_amdgcn_readfirstlane(t * 4);
        const float* xr = x + (size_t)n0 * 128;
        float acc[4] = {0.f, 0.f, 0.f, 0.f};
#pragma unroll
        for (int k = 0; k < 128; ++k) {
#pragma unroll
            for (int r = 0; r < 4; ++r) acc[r] = fmaf(xr[r * 128 + k], Wc[k], acc[r]);
        }
#pragma unroll
        for (int r = 0; r < 4; ++r) y[(size_t)(n0 + r) * 64 + l] = acc[r];
    }
}

// pre for GIN2/3: y = sk .* (h @ W), fp16 out. sk factored out of the GEMV so the
// broadcast operand is pure memory (uniform loads); sk==0 rows stay exactly 0.
__global__ __launch_bounds__(256) void k_pre23_h(const float* __restrict__ h,
                                                 const float* __restrict__ sk,
                                                 const float* __restrict__ W,
                                                 __half* __restrict__ yh) {
    int tid = threadIdx.x, w = tid >> 6, l = tid & 63;
    float Wc[64];
#pragma unroll
    for (int k = 0; k < 64; ++k) Wc[k] = W[k * 64 + l];
    int g = blockIdx.x * 4 + w;
    const int G = GVB * 4;
    for (int t = g; t < NN / 8; t += G) {
        int n0 = __builtin_amdgcn_readfirstlane(t * 8);
        const float* hr = h + (size_t)n0 * 64;
        float acc[8] = {0.f, 0.f, 0.f, 0.f, 0.f, 0.f, 0.f, 0.f};
#pragma unroll
        for (int k = 0; k < 64; ++k) {
#pragma unroll
            for (int r = 0; r < 8; ++r) acc[r] = fmaf(hr[r * 64 + k], Wc[k], acc[r]);
        }
#pragma unroll
        for (int r = 0; r < 8; ++r)
            yh[(size_t)(n0 + r) * 64 + l] = __float2half(acc[r] * sk[n0 + r]);
    }
}

// post: h = relu(z' @ W2 + b2) where z' = relu(z+b1) was pre-activated by the gather.
// mode 1: dinv from roffs-degree (pool1). mode 2: dinv from cnt & keep (pool2). mode 3: none.
__global__ __launch_bounds__(256) void k_post_g(const float* __restrict__ zp,
                                                const float* __restrict__ W2,
                                                const float* __restrict__ b2,
                                                const float* __restrict__ gW,
                                                const int* __restrict__ roffs,
                                                const int* __restrict__ cnt,
                                                const float* __restrict__ keep,
                                                float* __restrict__ hOut,
                                                float* __restrict__ hwd,
                                                float* __restrict__ dinv, int mode) {
    int tid = threadIdx.x, w = tid >> 6, l = tid & 63;
    float Wc[64];
#pragma unroll
    for (int k = 0; k < 64; ++k) Wc[k] = W2[k * 64 + l];
    float b2v = b2[l];
    float gWv = (mode < 3) ? gW[l] : 0.f;
    int g = blockIdx.x * 4 + w;
    const int G = GVB * 4;
    for (int t = g; t < NN / 8; t += G) {
        int n0 = __builtin_amdgcn_readfirstlane(t * 8);
        const float* zr = zp + (size_t)n0 * 64;
        float acc[8];
#pragma unroll
        for (int r = 0; r < 8; ++r) acc[r] = b2v;
#pragma unroll
        for (int k = 0; k < 64; ++k) {
#pragma unroll
            for (int r = 0; r < 8; ++r) acc[r] = fmaf(zr[r * 64 + k], Wc[k], acc[r]);
        }
#pragma unroll
        for (int r = 0; r < 8; ++r) {
            acc[r] = fmaxf(acc[r], 0.f);
            hOut[(size_t)(n0 + r) * 64 + l] = acc[r];
        }
        if (mode < 3) {
#pragma unroll
            for (int r = 0; r < 8; ++r) {
                float t2 = acc[r] * gWv;
                for (int o = 32; o > 0; o >>= 1) t2 += __shfl_down(t2, o, 64);
                if (l == 0) {
                    int n = n0 + r;
                    float di;
                    if (mode == 1) di = 1.f / sqrtf((float)(roffs[n + 1] - roffs[n]) + 1.f);
                    else di = (keep[n] != 0.f) ? 1.f / sqrtf((float)cnt[n] + 1.f) : 0.f;
                    dinv[n] = di;
                    hwd[n] = t2 * di;
                }
            }
        }
    }
}

// ---------------- fp32 CSR gather (GIN1), unroll-4; epilogue applies relu(z + b1) ---------
__global__ void k_gather_y(const float* __restrict__ y, const int* __restrict__ roffs,
                           const int* __restrict__ csrc, const float* __restrict__ b1,
                           float* __restrict__ z) {
    int tid = threadIdx.x;
    int d = blockIdx.x * 8 + (tid >> 5);
    int l = tid & 31;
    const float2* y2 = (const float2*)y;
    float2 acc = y2[(size_t)d * 32 + l];            // self term
    int e0 = roffs[d], e1 = roffs[d + 1];
    int e = e0;
    for (; e + 3 < e1; e += 4) {
        int s0 = csrc[e], s1 = csrc[e + 1], s2 = csrc[e + 2], s3 = csrc[e + 3];
        float2 v0 = y2[(size_t)s0 * 32 + l];
        float2 v1 = y2[(size_t)s1 * 32 + l];
        float2 v2 = y2[(size_t)s2 * 32 + l];
        float2 v3 = y2[(size_t)s3 * 32 + l];
        acc.x += (v0.x + v1.x) + (v2.x + v3.x);
        acc.y += (v0.y + v1.y) + (v2.y + v3.y);
    }
    for (; e < e1; ++e) {
        float2 v0 = y2[(size_t)csrc[e] * 32 + l];
        acc.x += v0.x; acc.y += v0.y;
    }
    float2 o;
    o.x = fmaxf(acc.x + b1[2 * l], 0.f);
    o.y = fmaxf(acc.y + b1[2 * l + 1], 0.f);
    ((float2*)z)[(size_t)d * 32 + l] = o;
}

// ---------------- fp16 CSR gather (GIN2/GIN3), unroll-4; epilogue relu(z + b1) ------------
__global__ void k_gather_h(const __half* __restrict__ yh, const int* __restrict__ roffs,
                           const int* __restrict__ csrc, const float* __restrict__ keepd,
                           const float* __restrict__ sk, const float* __restrict__ b1,
                           float* __restrict__ z, int* __restrict__ cnt) {
    int tid = threadIdx.x;
    int d = blockIdx.x * 8 + (tid >> 5);
    int l = tid & 31;
    const __half2* y2 = (const __half2*)yh;
    __half2 sv = y2[(size_t)d * 32 + l];
    float2 acc = make_float2(__low2float(sv), __high2float(sv));   // self term
    int c = 0;
    if (!keepd || keepd[d] != 0.f) {                // dst-side gate (wave-uniform)
        int e0 = roffs[d], e1 = roffs[d + 1];
        int e = e0;
        for (; e + 3 < e1; e += 4) {
            int s0 = csrc[e], s1 = csrc[e + 1], s2 = csrc[e + 2], s3 = csrc[e + 3];
            __half2 v0 = y2[(size_t)s0 * 32 + l];
            __half2 v1 = y2[(size_t)s1 * 32 + l];
            __half2 v2 = y2[(size_t)s2 * 32 + l];
            __half2 v3 = y2[(size_t)s3 * 32 + l];
            acc.x += (__low2float(v0) + __low2float(v1)) + (__low2float(v2) + __low2float(v3));
            acc.y += (__high2float(v0) + __high2float(v1)) + (__high2float(v2) + __high2float(v3));
            if (sk) c += (sk[s0] > 0.f) + (sk[s1] > 0.f) + (sk[s2] > 0.f) + (sk[s3] > 0.f);
        }
        for (; e < e1; ++e) {
            int s0 = csrc[e];
            __half2 v0 = y2[(size_t)s0 * 32 + l];
            acc.x += __low2float(v0); acc.y += __high2float(v0);
            if (sk) c += (sk[s0] > 0.f);
        }
    }
    float2 o;
    o.x = fmaxf(acc.x + b1[2 * l], 0.f);
    o.y = fmaxf(acc.y + b1[2 * l + 1], 0.f);
    ((float2*)z)[(size_t)d * 32 + l] = o;
    if (cnt && l == 0) cnt[d] = c;
}

// ---------------- attention gather: attn[i] = dinv[i]*(sum_nbr hwd + hwd[i]) + gb ----------------
__global__ void k_attn(const int* __restrict__ roffs, const int* __restrict__ csrc,
                       const float* __restrict__ hwd, const float* __restrict__ dinv,
                       const float* __restrict__ gb, float* __restrict__ attn) {
    int i = blockIdx.x * 256 + threadIdx.x;
    if (i >= NN) return;
    float sum = hwd[i];
    int e0 = roffs[i], e1 = roffs[i + 1];
    for (int e = e0; e < e1; ++e) sum += hwd[csrc[e]];
    attn[i] = dinv[i] * sum + gb[0];
}

// ---------------- per-graph softmax + threshold; also emits sk = score*keep ----------------
__global__ void k_softmax_pool(const float* __restrict__ attn, const float* __restrict__ nmask,
                               const int* __restrict__ offs, float* __restrict__ score,
                               float* __restrict__ keep, float* __restrict__ sk) {
    int b = blockIdx.x, tid = threadIdx.x;
    int s0 = offs[b], s1 = offs[b + 1];
    __shared__ float red[256];
    float m = NEGF;
    for (int i = s0 + tid; i < s1; i += 256) {
        float nm = nmask ? nmask[i] : 1.f;
        if (nm > 0.f) m = fmaxf(m, attn[i]);
    }
    red[tid] = m; __syncthreads();
    for (int o = 128; o > 0; o >>= 1) { if (tid < o) red[tid] = fmaxf(red[tid], red[tid + o]); __syncthreads(); }
    m = red[0]; __syncthreads();
    float s = 0.f;
    for (int i = s0 + tid; i < s1; i += 256) {
        float nm = nmask ? nmask[i] : 1.f;
        if (nm > 0.f) s += expf(attn[i] - m);
    }
    red[tid] = s; __syncthreads();
    for (int o = 128; o > 0; o >>= 1) { if (tid < o) red[tid] += red[tid + o]; __syncthreads(); }
    s = red[0]; __syncthreads();
    float sden = fmaxf(s, 1e-30f);
    float smax = NEGF;
    for (int i = s0 + tid; i < s1; i += 256) {
        float nm = nmask ? nmask[i] : 1.f;
        float sc = (nm > 0.f) ? expf(attn[i] - m) / sden : 0.f;
        score[i] = sc;
        smax = fmaxf(smax, (nm > 0.f) ? sc : NEGF);
    }
    red[tid] = smax; __syncthreads();
    for (int o = 128; o > 0; o >>= 1) { if (tid < o) red[tid] = fmaxf(red[tid], red[tid + o]); __syncthreads(); }
    smax = red[0]; __syncthreads();
    float thr = fminf(1e-3f, smax - 1e-7f);
    for (int i = s0 + tid; i < s1; i += 256) {
        float nm = nmask ? nmask[i] : 1.f;
        float sc = score[i];
        float kp = (nm > 0.f && sc > thr) ? 1.f : 0.f;
        keep[i] = kp;
        sk[i] = sc * kp;
    }
}

// ---------------- output head ----------------
__global__ void k_gmax_linear(const float* __restrict__ h, const float* __restrict__ keep2,
                              const int* __restrict__ offs, const float* __restrict__ Wl,
                              const float* __restrict__ bl, float* __restrict__ out) {
    int b = blockIdx.x, tid = threadIdx.x;
    int s0 = offs[b], s1 = offs[b + 1];
    int f = tid & 63, g = tid >> 6;
    float m = NEGF;
    for (int i = s0 + g; i < s1; i += 4)
        if (keep2[i] > 0.f) m = fmaxf(m, h[(size_t)i * 64 + f]);
    __shared__ float red[256];
    red[tid] = m; __syncthreads();
    if (g == 0) {
        m = fmaxf(fmaxf(red[f], red[64 + f]), fmaxf(red[128 + f], red[192 + f]));
        float v = m * Wl[f];
        for (int o = 32; o > 0; o >>= 1) v += __shfl_down(v, o, 64);
        if (f == 0) out[b] = v + bl[0];
    }
}

// ---------------- prefix sum of keep1 (exact int) ----------------
__global__ void k_scan1(const float* __restrict__ keep1, int* __restrict__ prefix,
                        int* __restrict__ bsums) {
    int blk = blockIdx.x, tid = threadIdx.x;
    int base = blk * 1024;
    int vals[4], tsum = 0;
    for (int j = 0; j < 4; ++j) {
        int idx = base + tid * 4 + j;
        int v = (idx < NN && keep1[idx] > 0.f) ? 1 : 0;
        tsum += v; vals[j] = tsum;
    }
    __shared__ int sh[256];
    sh[tid] = tsum; __syncthreads();
    for (int o = 1; o < 256; o <<= 1) {
        int v = (tid >= o) ? sh[tid - o] : 0;
        __syncthreads();
        sh[tid] += v;
        __syncthreads();
    }
    int excl = sh[tid] - tsum;
    for (int j = 0; j < 4; ++j) {
        int idx = base + tid * 4 + j;
        if (idx < NN) prefix[idx] = excl + vals[j];
    }
    if (tid == 255) bsums[blk] = sh[255];
}
__global__ void k_scan3(int* __restrict__ prefix, const int* __restrict__ boffs) {
    int idx = blockIdx.x * 256 + threadIdx.x;
    if (idx < NN) prefix[idx] += boffs[idx >> 10];
}

// ---------------- attention KL loss + ratio ----------------
__global__ void k_kl(const float* __restrict__ score2, const float* __restrict__ keep2,
                     const int* __restrict__ prefix, const float* __restrict__ natt,
                     const int* __restrict__ offs, float* __restrict__ out_loss,
                     float* __restrict__ c_total) {
    int b = blockIdx.x, tid = threadIdx.x;
    int s0 = offs[b], s1 = offs[b + 1];
    float s = 0.f, c = 0.f;
    for (int i = s0 + tid; i < s1; i += 256) {
        if (keep2[i] > 0.f) {
            int r1 = prefix[i] - 1;
            r1 = max(0, min(r1, NN - 1));
            float t = natt[r1];
            float logp = logf(score2[i] + 1e-14f);
            float kl = ((t > 0.f) ? t * logf(fmaxf(t, 1e-38f)) : 0.f) - t * logp;
            s += kl; c += 1.f;
        }
    }
    __shared__ float rs[256], rc[256];
    rs[tid] = s; rc[tid] = c; __syncthreads();
    for (int o = 128; o > 0; o >>= 1) {
        if (tid < o) { rs[tid] += rs[tid + o]; rc[tid] += rc[tid + o]; }
        __syncthreads();
    }
    if (tid == 0) {
        out_loss[b] = rs[0] / fmaxf(rc[0], 1.f);
        atomicAdd(c_total, rc[0]);
    }
}
__global__ void k_final(const float* __restrict__ c_total, float* __restrict__ out) {
    out[0] = c_total[0] / (float)NN;
}

extern "C" void kernel_launch(void* const* d_in, const int* in_sizes, int n_in,
                              void* d_out, int out_size, void* d_ws, size_t ws_size,
                              hipStream_t stream) {
    const float* x    = (const float*)d_in[0];
    const int*   src  = (const int*)d_in[1];
    const int*   dst  = (const int*)d_in[2];
    const int*   batch= (const int*)d_in[3];
    const float* natt = (const float*)d_in[4];
    const float* W11 = (const float*)d_in[5],  *b11 = (const float*)d_in[6];
    const float* W12 = (const float*)d_in[7],  *b12 = (const float*)d_in[8];
    const float* gW1 = (const float*)d_in[9],  *gb1 = (const float*)d_in[10];
    const float* W21 = (const float*)d_in[11], *b21 = (const float*)d_in[12];
    const float* W22 = (const float*)d_in[13], *b22 = (const float*)d_in[14];
    const float* gW2 = (const float*)d_in[15], *gb2 = (const float*)d_in[16];
    const float* W31 = (const float*)d_in[17], *b31 = (const float*)d_in[18];
    const float* W32 = (const float*)d_in[19], *b32 = (const float*)d_in[20];
    const float* Wl  = (const float*)d_in[21], *bl  = (const float*)d_in[22];
    float* out = (float*)d_out;

    // workspace layout
    float* hA     = (float*)d_ws;                 // N*64  (reused as h3)
    float* hB     = hA + (size_t)NN * 64;         // N*64
    float* ybuf   = hB + (size_t)NN * 64;         // N*64  (CSR build: H/Hs; fp16 y aliases)
    float* zbuf   = ybuf + (size_t)NN * 64;       // N*64  (CSR build: ebuf aliases)
    float* hwd    = zbuf + (size_t)NN * 64;       // N
    float* dinv   = hwd + NN;                     // N
    float* attn   = dinv + NN;                    // N
    float* score1 = attn + NN;                    // N
    float* keep1  = score1 + NN;                  // N
    float* sk1    = keep1 + NN;                   // N
    float* score2 = sk1 + NN;                     // N
    float* keep2  = score2 + NN;                  // N
    float* sk2    = keep2 + NN;                   // N
    int*   prefix = (int*)(sk2 + NN);             // N
    int*   cnt    = prefix + NN;                  // N
    int*   roffs  = cnt + NN;                     // N+1
    int*   csrc   = roffs + NN + 1;               // E
    int*   offs   = csrc + NE;                    // B+1
    int*   bsums  = offs + NB + 1;                // 128
    float* c_total= (float*)(bsums + 128);        // 1
    // CSR-build scratch aliases (dead regions during build)
    int*   H      = (int*)ybuf;                   // NBKT*P_SORT
    int*   Hs     = H + HLEN;                     // NBKT*P_SORT
    int2*  ebuf   = (int2*)zbuf;                  // E pairs (12.8 MB <= 25.6 MB region)
    __half* yh    = (__half*)ybuf;                // fp16 y for GIN2/3

    const int nblk_n  = (NN + 255) / 256;
    const int nblk_n8 = NN / 8;

    // graph offsets (batch sorted -> binary search)
    k_offs_bs<<<2, 256, 0, stream>>>(batch, offs);

    // CSR by dst: coarse hist -> scan -> pair scatter -> per-bucket LDS CSR
    k_hist_coarse<<<P_SORT, 256, 0, stream>>>(dst, H);
    k_iscan_blk<<<HSCAN_BLK, 256, 0, stream>>>(H, Hs, bsums, HLEN);
    k_iscan_mid<<<1, 1, 0, stream>>>(bsums, HSCAN_BLK);
    k_iscan_add<<<(HLEN + 255) / 256, 256, 0, stream>>>(Hs, bsums, HLEN);
    k_scatter_pairs<<<P_SORT, 256, 0, stream>>>(src, dst, Hs, ebuf);
    k_bucket_csr<<<NBKT, 256, 0, stream>>>(ebuf, Hs, roffs, csrc);

    // ---- GIN1: pre-GEMM (fp32) + gather (fp32, +relu/bias) + post ----
    k_pre1_g<<<GVB, 256, 0, stream>>>(x, W11, ybuf);
    k_gather_y<<<nblk_n8, 256, 0, stream>>>(ybuf, roffs, csrc, b11, zbuf);
    k_post_g<<<GVB, 256, 0, stream>>>(zbuf, W12, b12, gW1, roffs, nullptr, nullptr,
                                      hA, hwd, dinv, 1);
    k_attn<<<nblk_n, 256, 0, stream>>>(roffs, csrc, hwd, dinv, gb1, attn);
    k_softmax_pool<<<NB, 256, 0, stream>>>(attn, nullptr, offs, score1, keep1, sk1);

    // ---- GIN2 (fp16 gather payload) ----
    k_pre23_h<<<GVB, 256, 0, stream>>>(hA, sk1, W21, yh);
    k_gather_h<<<nblk_n8, 256, 0, stream>>>(yh, roffs, csrc, keep1, sk1, b21, zbuf, cnt);
    k_post_g<<<GVB, 256, 0, stream>>>(zbuf, W22, b22, gW2, roffs, cnt, keep1,
                                      hB, hwd, dinv, 2);
    k_attn<<<nblk_n, 256, 0, stream>>>(roffs, csrc, hwd, dinv, gb2, attn);
    k_softmax_pool<<<NB, 256, 0, stream>>>(attn, keep1, offs, score2, keep2, sk2);

    // ---- GIN3 (fp16 gather payload; h3 written into hA buffer) ----
    k_pre23_h<<<GVB, 256, 0, stream>>>(hB, sk2, W31, yh);
    k_gather_h<<<nblk_n8, 256, 0, stream>>>(yh, roffs, csrc, keep2, nullptr, b31, zbuf, nullptr);
    k_post_g<<<GVB, 256, 0, stream>>>(zbuf, W32, b32, nullptr, roffs, nullptr, nullptr,
                                      hA, nullptr, nullptr, 3);

    // ---- head: global max pool + linear ----
    k_gmax_linear<<<NB, 256, 0, stream>>>(hA, keep2, offs, Wl, bl, out);

    // ---- attention KL loss + ratio ----
    k_scan1<<<NSCAN_BLK, 256, 0, stream>>>(keep1, prefix, bsums);
    k_iscan_mid<<<1, 1, 0, stream>>>(bsums, NSCAN_BLK);
    k_scan3<<<nblk_n, 256, 0, stream>>>(prefix, bsums);
    hipMemsetAsync(c_total, 0, sizeof(float), stream);
    k_kl<<<NB, 256, 0, stream>>>(score2, keep2, prefix, natt, offs, out + NB, c_total);
    k_final<<<1, 1, 0, stream>>>(c_total, out + 2 * NB);
}

// Round 12
// 551.217 us; speedup vs baseline: 1.0839x; 1.0839x over previous
//
#include <hip/hip_runtime.h>
#include <hip/hip_fp16.h>
#include <math.h>

#define NN 100000
#define NE 1600000
#define NB 256
#define NEGF (-1e30f)
#define NSCAN_BLK ((NN + 1023) / 1024)
#define GVB 1024            // grid-stride GEMV blocks
#define P_SORT 256          // blocks in coarse histogram/scatter
#define NBKT 391            // ceil(NN/256) coarse buckets (dst>>8)
#define HLEN (NBKT * P_SORT)
#define HSCAN_BLK ((HLEN + 1023) / 1024)
#define BKT_CAP 6144        // LDS staging ints (24 KB); avg bucket = 4096 edges

// ---------------- graph offsets via binary search (batch is sorted) ----------------
__global__ void k_offs_bs(const int* __restrict__ batch, int* __restrict__ offs) {
    int g = blockIdx.x * 256 + threadIdx.x;
    if (g > NB) return;
    int lo = 0, hi = NN;
    while (lo < hi) { int mid = (lo + hi) >> 1; if (batch[mid] < g) lo = mid + 1; else hi = mid; }
    offs[g] = lo;
}

// ---------------- CSR build: two-level counting sort ----------------
__global__ void k_hist_coarse(const int* __restrict__ dst, int* __restrict__ H) {
    __shared__ int lh[NBKT];
    int p = blockIdx.x, tid = threadIdx.x;
    for (int i = tid; i < NBKT; i += 256) lh[i] = 0;
    __syncthreads();
    int c0 = p * (NE / P_SORT), c1 = c0 + NE / P_SORT;
    for (int i = c0 + tid; i < c1; i += 256) atomicAdd(&lh[dst[i] >> 8], 1);
    __syncthreads();
    for (int i = tid; i < NBKT; i += 256) H[i * P_SORT + p] = lh[i];
}
__global__ void k_iscan_blk(const int* __restrict__ in, int* __restrict__ pref,
                            int* __restrict__ bsums, int len) {
    int blk = blockIdx.x, tid = threadIdx.x;
    int base = blk * 1024;
    int vals[4], tsum = 0;
    for (int j = 0; j < 4; ++j) {
        int idx = base + tid * 4 + j;
        int v = (idx < len) ? in[idx] : 0;
        vals[j] = tsum; tsum += v;               // exclusive within thread
    }
    __shared__ int sh[256];
    sh[tid] = tsum; __syncthreads();
    for (int o = 1; o < 256; o <<= 1) {
        int v = (tid >= o) ? sh[tid - o] : 0;
        __syncthreads();
        sh[tid] += v;
        __syncthreads();
    }
    int excl = sh[tid] - tsum;
    for (int j = 0; j < 4; ++j) {
        int idx = base + tid * 4 + j;
        if (idx < len) pref[idx] = excl + vals[j];
    }
    if (tid == 255) bsums[blk] = sh[255];
}
__global__ void k_iscan_mid(int* __restrict__ bsums, int nb) {
    int acc = 0;
    for (int i = 0; i < nb; ++i) { int v = bsums[i]; bsums[i] = acc; acc += v; }
}
__global__ void k_iscan_add(int* __restrict__ pref, const int* __restrict__ bsums, int len) {
    int idx = blockIdx.x * 256 + threadIdx.x;
    if (idx < len) pref[idx] += bsums[idx >> 10];
}
__global__ void k_scatter_pairs(const int* __restrict__ src, const int* __restrict__ dst,
                                const int* __restrict__ Hs, int2* __restrict__ ebuf) {
    __shared__ int curs[NBKT];
    int p = blockIdx.x, tid = threadIdx.x;
    for (int i = tid; i < NBKT; i += 256) curs[i] = Hs[i * P_SORT + p];
    __syncthreads();
    int c0 = p * (NE / P_SORT), c1 = c0 + NE / P_SORT;
    for (int i = c0 + tid; i < c1; i += 256) {
        int d = dst[i];
        int pos = atomicAdd(&curs[d >> 8], 1);
        ebuf[pos] = make_int2(src[i], d);
    }
}
__global__ void k_bucket_csr(const int2* __restrict__ ebuf, const int* __restrict__ Hs,
                             int* __restrict__ roffs, int* __restrict__ csrc) {
    __shared__ int hist2[256];
    __shared__ int curs2[256];
    __shared__ int sh[256];
    __shared__ int stage[BKT_CAP];
    int b = blockIdx.x, tid = threadIdx.x;
    int e0 = Hs[b * P_SORT];
    int e1 = (b + 1 < NBKT) ? Hs[(b + 1) * P_SORT] : NE;
    int n0 = b * 256;
    int cntb = e1 - e0;
    if (b == 0 && tid == 0) roffs[NN] = NE;
    hist2[tid] = 0;
    __syncthreads();
    for (int i = e0 + tid; i < e1; i += 256) atomicAdd(&hist2[ebuf[i].y & 255], 1);
    __syncthreads();
    int v = hist2[tid];
    sh[tid] = v; __syncthreads();
    for (int o = 1; o < 256; o <<= 1) {
        int u = (tid >= o) ? sh[tid - o] : 0;
        __syncthreads();
        sh[tid] += u;
        __syncthreads();
    }
    int excl = sh[tid] - v;
    int node = n0 + tid;
    if (node < NN) roffs[node] = e0 + excl;
    curs2[tid] = excl;
    __syncthreads();
    if (cntb <= BKT_CAP) {
        for (int i = e0 + tid; i < e1; i += 256) {
            int2 pr = ebuf[i];
            int pos = atomicAdd(&curs2[pr.y & 255], 1);
            stage[pos] = pr.x;
        }
        __syncthreads();
        for (int i = tid; i < cntb; i += 256) csrc[e0 + i] = stage[i];
    } else {
        for (int i = e0 + tid; i < e1; i += 256) {
            int2 pr = ebuf[i];
            int pos = atomicAdd(&curs2[pr.y & 255], 1);
            csrc[e0 + pos] = pr.x;
        }
    }
}

// ---------------- GEMV kernels: W in VGPRs, broadcast via wave-local LDS ds_read_b128 -----
// pre1: y = x @ W11 (K=128, R=4 rows/tile)
__global__ __launch_bounds__(256) void k_pre1_g(const float* __restrict__ x,
                                                const float* __restrict__ W,
                                                float* __restrict__ y) {
    __shared__ float lds[4][4 * 128];
    int tid = threadIdx.x, w = tid >> 6, l = tid & 63;
    float Wc[128];
#pragma unroll
    for (int k = 0; k < 128; ++k) Wc[k] = W[k * 64 + l];
    float* row = lds[w];
    int g = blockIdx.x * 4 + w;
    const int G = GVB * 4;
    for (int t = g; t < NN / 4; t += G) {
        int n0 = t * 4;
#pragma unroll
        for (int r = 0; r < 4; ++r) {
            row[r * 128 + l]      = x[(size_t)(n0 + r) * 128 + l];
            row[r * 128 + 64 + l] = x[(size_t)(n0 + r) * 128 + 64 + l];
        }
        __builtin_amdgcn_wave_barrier();
        float acc[4] = {0.f, 0.f, 0.f, 0.f};
#pragma unroll
        for (int k = 0; k < 128; k += 4) {
#pragma unroll
            for (int r = 0; r < 4; ++r) {
                float4 bv = *(const float4*)&row[r * 128 + k];   // uniform addr -> LDS broadcast
                acc[r] = fmaf(bv.x, Wc[k],     acc[r]);
                acc[r] = fmaf(bv.y, Wc[k + 1], acc[r]);
                acc[r] = fmaf(bv.z, Wc[k + 2], acc[r]);
                acc[r] = fmaf(bv.w, Wc[k + 3], acc[r]);
            }
        }
        __builtin_amdgcn_wave_barrier();
#pragma unroll
        for (int r = 0; r < 4; ++r) y[(size_t)(n0 + r) * 64 + l] = acc[r];
    }
}

// pre for GIN2/3: y = sk .* (h @ W), fp16 out (K=64, R=8). sk applied at writeback.
__global__ __launch_bounds__(256) void k_pre23_h(const float* __restrict__ h,
                                                 const float* __restrict__ sk,
                                                 const float* __restrict__ W,
                                                 __half* __restrict__ yh) {
    __shared__ float lds[4][8 * 64];
    int tid = threadIdx.x, w = tid >> 6, l = tid & 63;
    float Wc[64];
#pragma unroll
    for (int k = 0; k < 64; ++k) Wc[k] = W[k * 64 + l];
    float* row = lds[w];
    int g = blockIdx.x * 4 + w;
    const int G = GVB * 4;
    for (int t = g; t < NN / 8; t += G) {
        int n0 = t * 8;
#pragma unroll
        for (int r = 0; r < 8; ++r) row[r * 64 + l] = h[(size_t)(n0 + r) * 64 + l];
        __builtin_amdgcn_wave_barrier();
        float acc[8] = {0.f, 0.f, 0.f, 0.f, 0.f, 0.f, 0.f, 0.f};
#pragma unroll
        for (int k = 0; k < 64; k += 4) {
#pragma unroll
            for (int r = 0; r < 8; ++r) {
                float4 bv = *(const float4*)&row[r * 64 + k];
                acc[r] = fmaf(bv.x, Wc[k],     acc[r]);
                acc[r] = fmaf(bv.y, Wc[k + 1], acc[r]);
                acc[r] = fmaf(bv.z, Wc[k + 2], acc[r]);
                acc[r] = fmaf(bv.w, Wc[k + 3], acc[r]);
            }
        }
        __builtin_amdgcn_wave_barrier();
#pragma unroll
        for (int r = 0; r < 8; ++r)
            yh[(size_t)(n0 + r) * 64 + l] = __float2half(acc[r] * sk[n0 + r]);
    }
}

// post: h = relu(z' @ W2 + b2) where z' = relu(z+b1) was pre-activated by the gather.
// mode 1: dinv from roffs-degree (pool1). mode 2: dinv from cnt & keep (pool2). mode 3: none.
__global__ __launch_bounds__(256) void k_post_g(const float* __restrict__ zp,
                                                const float* __restrict__ W2,
                                                const float* __restrict__ b2,
                                                const float* __restrict__ gW,
                                                const int* __restrict__ roffs,
                                                const int* __restrict__ cnt,
                                                const float* __restrict__ keep,
                                                float* __restrict__ hOut,
                                                float* __restrict__ hwd,
                                                float* __restrict__ dinv, int mode) {
    __shared__ float lds[4][8 * 64];
    int tid = threadIdx.x, w = tid >> 6, l = tid & 63;
    float Wc[64];
#pragma unroll
    for (int k = 0; k < 64; ++k) Wc[k] = W2[k * 64 + l];
    float b2v = b2[l];
    float gWv = (mode < 3) ? gW[l] : 0.f;
    float* row = lds[w];
    int g = blockIdx.x * 4 + w;
    const int G = GVB * 4;
    for (int t = g; t < NN / 8; t += G) {
        int n0 = t * 8;
#pragma unroll
        for (int r = 0; r < 8; ++r) row[r * 64 + l] = zp[(size_t)(n0 + r) * 64 + l];
        __builtin_amdgcn_wave_barrier();
        float acc[8];
#pragma unroll
        for (int r = 0; r < 8; ++r) acc[r] = b2v;
#pragma unroll
        for (int k = 0; k < 64; k += 4) {
#pragma unroll
            for (int r = 0; r < 8; ++r) {
                float4 bv = *(const float4*)&row[r * 64 + k];
                acc[r] = fmaf(bv.x, Wc[k],     acc[r]);
                acc[r] = fmaf(bv.y, Wc[k + 1], acc[r]);
                acc[r] = fmaf(bv.z, Wc[k + 2], acc[r]);
                acc[r] = fmaf(bv.w, Wc[k + 3], acc[r]);
            }
        }
        __builtin_amdgcn_wave_barrier();
#pragma unroll
        for (int r = 0; r < 8; ++r) {
            acc[r] = fmaxf(acc[r], 0.f);
            hOut[(size_t)(n0 + r) * 64 + l] = acc[r];
        }
        if (mode < 3) {
#pragma unroll
            for (int r = 0; r < 8; ++r) {
                float t2 = acc[r] * gWv;
                for (int o = 32; o > 0; o >>= 1) t2 += __shfl_down(t2, o, 64);
                if (l == 0) {
                    int n = n0 + r;
                    float di;
                    if (mode == 1) di = 1.f / sqrtf((float)(roffs[n + 1] - roffs[n]) + 1.f);
                    else di = (keep[n] != 0.f) ? 1.f / sqrtf((float)cnt[n] + 1.f) : 0.f;
                    dinv[n] = di;
                    hwd[n] = t2 * di;
                }
            }
        }
    }
}

// ---------------- fp32 CSR gather (GIN1), unroll-4; epilogue applies relu(z + b1) ---------
__global__ void k_gather_y(const float* __restrict__ y, const int* __restrict__ roffs,
                           const int* __restrict__ csrc, const float* __restrict__ b1,
                           float* __restrict__ z) {
    int tid = threadIdx.x;
    int d = blockIdx.x * 8 + (tid >> 5);
    int l = tid & 31;
    const float2* y2 = (const float2*)y;
    float2 acc = y2[(size_t)d * 32 + l];            // self term
    int e0 = roffs[d], e1 = roffs[d + 1];
    int e = e0;
    for (; e + 3 < e1; e += 4) {
        int s0 = csrc[e], s1 = csrc[e + 1], s2 = csrc[e + 2], s3 = csrc[e + 3];
        float2 v0 = y2[(size_t)s0 * 32 + l];
        float2 v1 = y2[(size_t)s1 * 32 + l];
        float2 v2 = y2[(size_t)s2 * 32 + l];
        float2 v3 = y2[(size_t)s3 * 32 + l];
        acc.x += (v0.x + v1.x) + (v2.x + v3.x);
        acc.y += (v0.y + v1.y) + (v2.y + v3.y);
    }
    for (; e < e1; ++e) {
        float2 v0 = y2[(size_t)csrc[e] * 32 + l];
        acc.x += v0.x; acc.y += v0.y;
    }
    float2 o;
    o.x = fmaxf(acc.x + b1[2 * l], 0.f);
    o.y = fmaxf(acc.y + b1[2 * l + 1], 0.f);
    ((float2*)z)[(size_t)d * 32 + l] = o;
}

// ---------------- fp16 CSR gather (GIN2/GIN3), unroll-4; epilogue relu(z + b1) ------------
__global__ void k_gather_h(const __half* __restrict__ yh, const int* __restrict__ roffs,
                           const int* __restrict__ csrc, const float* __restrict__ keepd,
                           const float* __restrict__ sk, const float* __restrict__ b1,
                           float* __restrict__ z, int* __restrict__ cnt) {
    int tid = threadIdx.x;
    int d = blockIdx.x * 8 + (tid >> 5);
    int l = tid & 31;
    const __half2* y2 = (const __half2*)yh;
    __half2 sv = y2[(size_t)d * 32 + l];
    float2 acc = make_float2(__low2float(sv), __high2float(sv));   // self term
    int c = 0;
    if (!keepd || keepd[d] != 0.f) {                // dst-side gate (wave-uniform)
        int e0 = roffs[d], e1 = roffs[d + 1];
        int e = e0;
        for (; e + 3 < e1; e += 4) {
            int s0 = csrc[e], s1 = csrc[e + 1], s2 = csrc[e + 2], s3 = csrc[e + 3];
            __half2 v0 = y2[(size_t)s0 * 32 + l];
            __half2 v1 = y2[(size_t)s1 * 32 + l];
            __half2 v2 = y2[(size_t)s2 * 32 + l];
            __half2 v3 = y2[(size_t)s3 * 32 + l];
            acc.x += (__low2float(v0) + __low2float(v1)) + (__low2float(v2) + __low2float(v3));
            acc.y += (__high2float(v0) + __high2float(v1)) + (__high2float(v2) + __high2float(v3));
            if (sk) c += (sk[s0] > 0.f) + (sk[s1] > 0.f) + (sk[s2] > 0.f) + (sk[s3] > 0.f);
        }
        for (; e < e1; ++e) {
            int s0 = csrc[e];
            __half2 v0 = y2[(size_t)s0 * 32 + l];
            acc.x += __low2float(v0); acc.y += __high2float(v0);
            if (sk) c += (sk[s0] > 0.f);
        }
    }
    float2 o;
    o.x = fmaxf(acc.x + b1[2 * l], 0.f);
    o.y = fmaxf(acc.y + b1[2 * l + 1], 0.f);
    ((float2*)z)[(size_t)d * 32 + l] = o;
    if (cnt && l == 0) cnt[d] = c;
}

// ---------------- attention gather: attn[i] = dinv[i]*(sum_nbr hwd + hwd[i]) + gb ----------------
__global__ void k_attn(const int* __restrict__ roffs, const int* __restrict__ csrc,
                       const float* __restrict__ hwd, const float* __restrict__ dinv,
                       const float* __restrict__ gb, float* __restrict__ attn) {
    int i = blockIdx.x * 256 + threadIdx.x;
    if (i >= NN) return;
    float sum = hwd[i];
    int e0 = roffs[i], e1 = roffs[i + 1];
    for (int e = e0; e < e1; ++e) sum += hwd[csrc[e]];
    attn[i] = dinv[i] * sum + gb[0];
}

// ---------------- per-graph softmax + threshold; also emits sk = score*keep ----------------
__global__ void k_softmax_pool(const float* __restrict__ attn, const float* __restrict__ nmask,
                               const int* __restrict__ offs, float* __restrict__ score,
                               float* __restrict__ keep, float* __restrict__ sk) {
    int b = blockIdx.x, tid = threadIdx.x;
    int s0 = offs[b], s1 = offs[b + 1];
    __shared__ float red[256];
    float m = NEGF;
    for (int i = s0 + tid; i < s1; i += 256) {
        float nm = nmask ? nmask[i] : 1.f;
        if (nm > 0.f) m = fmaxf(m, attn[i]);
    }
    red[tid] = m; __syncthreads();
    for (int o = 128; o > 0; o >>= 1) { if (tid < o) red[tid] = fmaxf(red[tid], red[tid + o]); __syncthreads(); }
    m = red[0]; __syncthreads();
    float s = 0.f;
    for (int i = s0 + tid; i < s1; i += 256) {
        float nm = nmask ? nmask[i] : 1.f;
        if (nm > 0.f) s += expf(attn[i] - m);
    }
    red[tid] = s; __syncthreads();
    for (int o = 128; o > 0; o >>= 1) { if (tid < o) red[tid] += red[tid + o]; __syncthreads(); }
    s = red[0]; __syncthreads();
    float sden = fmaxf(s, 1e-30f);
    float smax = NEGF;
    for (int i = s0 + tid; i < s1; i += 256) {
        float nm = nmask ? nmask[i] : 1.f;
        float sc = (nm > 0.f) ? expf(attn[i] - m) / sden : 0.f;
        score[i] = sc;
        smax = fmaxf(smax, (nm > 0.f) ? sc : NEGF);
    }
    red[tid] = smax; __syncthreads();
    for (int o = 128; o > 0; o >>= 1) { if (tid < o) red[tid] = fmaxf(red[tid], red[tid + o]); __syncthreads(); }
    smax = red[0]; __syncthreads();
    float thr = fminf(1e-3f, smax - 1e-7f);
    for (int i = s0 + tid; i < s1; i += 256) {
        float nm = nmask ? nmask[i] : 1.f;
        float sc = score[i];
        float kp = (nm > 0.f && sc > thr) ? 1.f : 0.f;
        keep[i] = kp;
        sk[i] = sc * kp;
    }
}

// ---------------- output head ----------------
__global__ void k_gmax_linear(const float* __restrict__ h, const float* __restrict__ keep2,
                              const int* __restrict__ offs, const float* __restrict__ Wl,
                              const float* __restrict__ bl, float* __restrict__ out) {
    int b = blockIdx.x, tid = threadIdx.x;
    int s0 = offs[b], s1 = offs[b + 1];
    int f = tid & 63, g = tid >> 6;
    float m = NEGF;
    for (int i = s0 + g; i < s1; i += 4)
        if (keep2[i] > 0.f) m = fmaxf(m, h[(size_t)i * 64 + f]);
    __shared__ float red[256];
    red[tid] = m; __syncthreads();
    if (g == 0) {
        m = fmaxf(fmaxf(red[f], red[64 + f]), fmaxf(red[128 + f], red[192 + f]));
        float v = m * Wl[f];
        for (int o = 32; o > 0; o >>= 1) v += __shfl_down(v, o, 64);
        if (f == 0) out[b] = v + bl[0];
    }
}

// ---------------- prefix sum of keep1 (exact int) ----------------
__global__ void k_scan1(const float* __restrict__ keep1, int* __restrict__ prefix,
                        int* __restrict__ bsums) {
    int blk = blockIdx.x, tid = threadIdx.x;
    int base = blk * 1024;
    int vals[4], tsum = 0;
    for (int j = 0; j < 4; ++j) {
        int idx = base + tid * 4 + j;
        int v = (idx < NN && keep1[idx] > 0.f) ? 1 : 0;
        tsum += v; vals[j] = tsum;
    }
    __shared__ int sh[256];
    sh[tid] = tsum; __syncthreads();
    for (int o = 1; o < 256; o <<= 1) {
        int v = (tid >= o) ? sh[tid - o] : 0;
        __syncthreads();
        sh[tid] += v;
        __syncthreads();
    }
    int excl = sh[tid] - tsum;
    for (int j = 0; j < 4; ++j) {
        int idx = base + tid * 4 + j;
        if (idx < NN) prefix[idx] = excl + vals[j];
    }
    if (tid == 255) bsums[blk] = sh[255];
}
__global__ void k_scan3(int* __restrict__ prefix, const int* __restrict__ boffs) {
    int idx = blockIdx.x * 256 + threadIdx.x;
    if (idx < NN) prefix[idx] += boffs[idx >> 10];
}

// ---------------- attention KL loss + ratio ----------------
__global__ void k_kl(const float* __restrict__ score2, const float* __restrict__ keep2,
                     const int* __restrict__ prefix, const float* __restrict__ natt,
                     const int* __restrict__ offs, float* __restrict__ out_loss,
                     float* __restrict__ c_total) {
    int b = blockIdx.x, tid = threadIdx.x;
    int s0 = offs[b], s1 = offs[b + 1];
    float s = 0.f, c = 0.f;
    for (int i = s0 + tid; i < s1; i += 256) {
        if (keep2[i] > 0.f) {
            int r1 = prefix[i] - 1;
            r1 = max(0, min(r1, NN - 1));
            float t = natt[r1];
            float logp = logf(score2[i] + 1e-14f);
            float kl = ((t > 0.f) ? t * logf(fmaxf(t, 1e-38f)) : 0.f) - t * logp;
            s += kl; c += 1.f;
        }
    }
    __shared__ float rs[256], rc[256];
    rs[tid] = s; rc[tid] = c; __syncthreads();
    for (int o = 128; o > 0; o >>= 1) {
        if (tid < o) { rs[tid] += rs[tid + o]; rc[tid] += rc[tid + o]; }
        __syncthreads();
    }
    if (tid == 0) {
        out_loss[b] = rs[0] / fmaxf(rc[0], 1.f);
        atomicAdd(c_total, rc[0]);
    }
}
__global__ void k_final(const float* __restrict__ c_total, float* __restrict__ out) {
    out[0] = c_total[0] / (float)NN;
}

extern "C" void kernel_launch(void* const* d_in, const int* in_sizes, int n_in,
                              void* d_out, int out_size, void* d_ws, size_t ws_size,
                              hipStream_t stream) {
    const float* x    = (const float*)d_in[0];
    const int*   src  = (const int*)d_in[1];
    const int*   dst  = (const int*)d_in[2];
    const int*   batch= (const int*)d_in[3];
    const float* natt = (const float*)d_in[4];
    const float* W11 = (const float*)d_in[5],  *b11 = (const float*)d_in[6];
    const float* W12 = (const float*)d_in[7],  *b12 = (const float*)d_in[8];
    const float* gW1 = (const float*)d_in[9],  *gb1 = (const float*)d_in[10];
    const float* W21 = (const float*)d_in[11], *b21 = (const float*)d_in[12];
    const float* W22 = (const float*)d_in[13], *b22 = (const float*)d_in[14];
    const float* gW2 = (const float*)d_in[15], *gb2 = (const float*)d_in[16];
    const float* W31 = (const float*)d_in[17], *b31 = (const float*)d_in[18];
    const float* W32 = (const float*)d_in[19], *b32 = (const float*)d_in[20];
    const float* Wl  = (const float*)d_in[21], *bl  = (const float*)d_in[22];
    float* out = (float*)d_out;

    // workspace layout
    float* hA     = (float*)d_ws;                 // N*64  (reused as h3)
    float* hB     = hA + (size_t)NN * 64;         // N*64
    float* ybuf   = hB + (size_t)NN * 64;         // N*64  (CSR build: H/Hs; fp16 y aliases)
    float* zbuf   = ybuf + (size_t)NN * 64;       // N*64  (CSR build: ebuf aliases)
    float* hwd    = zbuf + (size_t)NN * 64;       // N
    float* dinv   = hwd + NN;                     // N
    float* attn   = dinv + NN;                    // N
    float* score1 = attn + NN;                    // N
    float* keep1  = score1 + NN;                  // N
    float* sk1    = keep1 + NN;                   // N
    float* score2 = sk1 + NN;                     // N
    float* keep2  = score2 + NN;                  // N
    float* sk2    = keep2 + NN;                   // N
    int*   prefix = (int*)(sk2 + NN);             // N
    int*   cnt    = prefix + NN;                  // N
    int*   roffs  = cnt + NN;                     // N+1
    int*   csrc   = roffs + NN + 1;               // E
    int*   offs   = csrc + NE;                    // B+1
    int*   bsums  = offs + NB + 1;                // 128
    float* c_total= (float*)(bsums + 128);        // 1
    // CSR-build scratch aliases (dead regions during build)
    int*   H      = (int*)ybuf;                   // NBKT*P_SORT
    int*   Hs     = H + HLEN;                     // NBKT*P_SORT
    int2*  ebuf   = (int2*)zbuf;                  // E pairs (12.8 MB <= 25.6 MB region)
    __half* yh    = (__half*)ybuf;                // fp16 y for GIN2/3

    const int nblk_n  = (NN + 255) / 256;
    const int nblk_n8 = NN / 8;

    // graph offsets (batch sorted -> binary search)
    k_offs_bs<<<2, 256, 0, stream>>>(batch, offs);

    // CSR by dst: coarse hist -> scan -> pair scatter -> per-bucket LDS CSR
    k_hist_coarse<<<P_SORT, 256, 0, stream>>>(dst, H);
    k_iscan_blk<<<HSCAN_BLK, 256, 0, stream>>>(H, Hs, bsums, HLEN);
    k_iscan_mid<<<1, 1, 0, stream>>>(bsums, HSCAN_BLK);
    k_iscan_add<<<(HLEN + 255) / 256, 256, 0, stream>>>(Hs, bsums, HLEN);
    k_scatter_pairs<<<P_SORT, 256, 0, stream>>>(src, dst, Hs, ebuf);
    k_bucket_csr<<<NBKT, 256, 0, stream>>>(ebuf, Hs, roffs, csrc);

    // ---- GIN1: pre-GEMM (fp32) + gather (fp32, +relu/bias) + post ----
    k_pre1_g<<<GVB, 256, 0, stream>>>(x, W11, ybuf);
    k_gather_y<<<nblk_n8, 256, 0, stream>>>(ybuf, roffs, csrc, b11, zbuf);
    k_post_g<<<GVB, 256, 0, stream>>>(zbuf, W12, b12, gW1, roffs, nullptr, nullptr,
                                      hA, hwd, dinv, 1);
    k_attn<<<nblk_n, 256, 0, stream>>>(roffs, csrc, hwd, dinv, gb1, attn);
    k_softmax_pool<<<NB, 256, 0, stream>>>(attn, nullptr, offs, score1, keep1, sk1);

    // ---- GIN2 (fp16 gather payload) ----
    k_pre23_h<<<GVB, 256, 0, stream>>>(hA, sk1, W21, yh);
    k_gather_h<<<nblk_n8, 256, 0, stream>>>(yh, roffs, csrc, keep1, sk1, b21, zbuf, cnt);
    k_post_g<<<GVB, 256, 0, stream>>>(zbuf, W22, b22, gW2, roffs, cnt, keep1,
                                      hB, hwd, dinv, 2);
    k_attn<<<nblk_n, 256, 0, stream>>>(roffs, csrc, hwd, dinv, gb2, attn);
    k_softmax_pool<<<NB, 256, 0, stream>>>(attn, keep1, offs, score2, keep2, sk2);

    // ---- GIN3 (fp16 gather payload; h3 written into hA buffer) ----
    k_pre23_h<<<GVB, 256, 0, stream>>>(hB, sk2, W31, yh);
    k_gather_h<<<nblk_n8, 256, 0, stream>>>(yh, roffs, csrc, keep2, nullptr, b31, zbuf, nullptr);
    k_post_g<<<GVB, 256, 0, stream>>>(zbuf, W32, b32, nullptr, roffs, nullptr, nullptr,
                                      hA, nullptr, nullptr, 3);

    // ---- head: global max pool + linear ----
    k_gmax_linear<<<NB, 256, 0, stream>>>(hA, keep2, offs, Wl, bl, out);

    // ---- attention KL loss + ratio ----
    k_scan1<<<NSCAN_BLK, 256, 0, stream>>>(keep1, prefix, bsums);
    k_iscan_mid<<<1, 1, 0, stream>>>(bsums, NSCAN_BLK);
    k_scan3<<<nblk_n, 256, 0, stream>>>(prefix, bsums);
    hipMemsetAsync(c_total, 0, sizeof(float), stream);
    k_kl<<<NB, 256, 0, stream>>>(score2, keep2, prefix, natt, offs, out + NB, c_total);
    k_final<<<1, 1, 0, stream>>>(c_total, out + 2 * NB);
}

// Round 13
// 508.150 us; speedup vs baseline: 1.1758x; 1.0848x over previous
//
#include <hip/hip_runtime.h>
#include <hip/hip_fp16.h>
#include <math.h>

#define NN 100000
#define NE 1600000
#define NB 256
#define NEGF (-1e30f)
#define NSCAN_BLK ((NN + 1023) / 1024)
#define GVB 1024            // grid-stride GEMV blocks
#define P_SORT 256          // blocks in coarse histogram/scatter
#define NBKT 391            // ceil(NN/256) coarse buckets (dst>>8)
#define HLEN (NBKT * P_SORT)
#define HSCAN_BLK ((HLEN + 1023) / 1024)
#define BKT_CAP 6144        // LDS staging ints (24 KB); avg bucket = 4096 edges

// ---------------- CSR build: two-level counting sort ----------------
// coarse histogram; block 0 also computes per-graph offsets (batch sorted, binary search)
__global__ void k_hist_coarse(const int* __restrict__ dst, const int* __restrict__ batch,
                              int* __restrict__ offs, int* __restrict__ H) {
    __shared__ int lh[NBKT];
    int p = blockIdx.x, tid = threadIdx.x;
    if (p == 0) {
        for (int g = tid; g <= NB; g += 256) {
            int lo = 0, hi = NN;
            while (lo < hi) { int mid = (lo + hi) >> 1; if (batch[mid] < g) lo = mid + 1; else hi = mid; }
            offs[g] = lo;
        }
    }
    for (int i = tid; i < NBKT; i += 256) lh[i] = 0;
    __syncthreads();
    int c0 = p * (NE / P_SORT), c1 = c0 + NE / P_SORT;
    for (int i = c0 + tid; i < c1; i += 256) atomicAdd(&lh[dst[i] >> 8], 1);
    __syncthreads();
    for (int i = tid; i < NBKT; i += 256) H[i * P_SORT + p] = lh[i];
}
__global__ void k_iscan_blk(const int* __restrict__ in, int* __restrict__ pref,
                            int* __restrict__ bsums, int len) {
    int blk = blockIdx.x, tid = threadIdx.x;
    int base = blk * 1024;
    int vals[4], tsum = 0;
    for (int j = 0; j < 4; ++j) {
        int idx = base + tid * 4 + j;
        int v = (idx < len) ? in[idx] : 0;
        vals[j] = tsum; tsum += v;               // exclusive within thread
    }
    __shared__ int sh[256];
    sh[tid] = tsum; __syncthreads();
    for (int o = 1; o < 256; o <<= 1) {
        int v = (tid >= o) ? sh[tid - o] : 0;
        __syncthreads();
        sh[tid] += v;
        __syncthreads();
    }
    int excl = sh[tid] - tsum;
    for (int j = 0; j < 4; ++j) {
        int idx = base + tid * 4 + j;
        if (idx < len) pref[idx] = excl + vals[j];
    }
    if (tid == 255) bsums[blk] = sh[255];
}
// adds prefix of raw block sums (computed inline: block covers 256 idx -> one scan-block)
__global__ void k_iscan_add(int* __restrict__ pref, const int* __restrict__ bsums, int len) {
    __shared__ int sh[256];
    int t = threadIdx.x;
    int sb = blockIdx.x >> 2;                     // 1024-elem scan-block index (constant/block)
    sh[t] = (t < sb) ? bsums[t] : 0;
    __syncthreads();
    for (int o = 128; o > 0; o >>= 1) { if (t < o) sh[t] += sh[t + o]; __syncthreads(); }
    int pre = sh[0];
    int idx = blockIdx.x * 256 + t;
    if (idx < len) pref[idx] += pre;
}
__global__ void k_scatter_pairs(const int* __restrict__ src, const int* __restrict__ dst,
                                const int* __restrict__ Hs, int2* __restrict__ ebuf) {
    __shared__ int curs[NBKT];
    int p = blockIdx.x, tid = threadIdx.x;
    for (int i = tid; i < NBKT; i += 256) curs[i] = Hs[i * P_SORT + p];
    __syncthreads();
    int c0 = p * (NE / P_SORT), c1 = c0 + NE / P_SORT;
    for (int i = c0 + tid; i < c1; i += 256) {
        int d = dst[i];
        int pos = atomicAdd(&curs[d >> 8], 1);
        ebuf[pos] = make_int2(src[i], d);
    }
}
__global__ void k_bucket_csr(const int2* __restrict__ ebuf, const int* __restrict__ Hs,
                             int* __restrict__ roffs, int* __restrict__ csrc) {
    __shared__ int hist2[256];
    __shared__ int curs2[256];
    __shared__ int sh[256];
    __shared__ int stage[BKT_CAP];
    int b = blockIdx.x, tid = threadIdx.x;
    int e0 = Hs[b * P_SORT];
    int e1 = (b + 1 < NBKT) ? Hs[(b + 1) * P_SORT] : NE;
    int n0 = b * 256;
    int cntb = e1 - e0;
    if (b == 0 && tid == 0) roffs[NN] = NE;
    hist2[tid] = 0;
    __syncthreads();
    for (int i = e0 + tid; i < e1; i += 256) atomicAdd(&hist2[ebuf[i].y & 255], 1);
    __syncthreads();
    int v = hist2[tid];
    sh[tid] = v; __syncthreads();
    for (int o = 1; o < 256; o <<= 1) {
        int u = (tid >= o) ? sh[tid - o] : 0;
        __syncthreads();
        sh[tid] += u;
        __syncthreads();
    }
    int excl = sh[tid] - v;
    int node = n0 + tid;
    if (node < NN) roffs[node] = e0 + excl;
    curs2[tid] = excl;
    __syncthreads();
    if (cntb <= BKT_CAP) {
        for (int i = e0 + tid; i < e1; i += 256) {
            int2 pr = ebuf[i];
            int pos = atomicAdd(&curs2[pr.y & 255], 1);
            stage[pos] = pr.x;
        }
        __syncthreads();
        for (int i = tid; i < cntb; i += 256) csrc[e0 + i] = stage[i];
    } else {
        for (int i = e0 + tid; i < e1; i += 256) {
            int2 pr = ebuf[i];
            int pos = atomicAdd(&curs2[pr.y & 255], 1);
            csrc[e0 + pos] = pr.x;
        }
    }
}

// ---------------- GEMV kernels: W in VGPRs, broadcast via wave-local LDS ds_read_b128 -----
__global__ __launch_bounds__(256) void k_pre1_g(const float* __restrict__ x,
                                                const float* __restrict__ W,
                                                float* __restrict__ y) {
    __shared__ float lds[4][4 * 128];
    int tid = threadIdx.x, w = tid >> 6, l = tid & 63;
    float Wc[128];
#pragma unroll
    for (int k = 0; k < 128; ++k) Wc[k] = W[k * 64 + l];
    float* row = lds[w];
    int g = blockIdx.x * 4 + w;
    const int G = GVB * 4;
    for (int t = g; t < NN / 4; t += G) {
        int n0 = t * 4;
#pragma unroll
        for (int r = 0; r < 4; ++r) {
            row[r * 128 + l]      = x[(size_t)(n0 + r) * 128 + l];
            row[r * 128 + 64 + l] = x[(size_t)(n0 + r) * 128 + 64 + l];
        }
        __builtin_amdgcn_wave_barrier();
        float acc[4] = {0.f, 0.f, 0.f, 0.f};
#pragma unroll
        for (int k = 0; k < 128; k += 4) {
#pragma unroll
            for (int r = 0; r < 4; ++r) {
                float4 bv = *(const float4*)&row[r * 128 + k];   // uniform addr -> LDS broadcast
                acc[r] = fmaf(bv.x, Wc[k],     acc[r]);
                acc[r] = fmaf(bv.y, Wc[k + 1], acc[r]);
                acc[r] = fmaf(bv.z, Wc[k + 2], acc[r]);
                acc[r] = fmaf(bv.w, Wc[k + 3], acc[r]);
            }
        }
        __builtin_amdgcn_wave_barrier();
#pragma unroll
        for (int r = 0; r < 4; ++r) y[(size_t)(n0 + r) * 64 + l] = acc[r];
    }
}

__global__ __launch_bounds__(256) void k_pre23_h(const float* __restrict__ h,
                                                 const float* __restrict__ sk,
                                                 const float* __restrict__ W,
                                                 __half* __restrict__ yh) {
    __shared__ float lds[4][8 * 64];
    int tid = threadIdx.x, w = tid >> 6, l = tid & 63;
    float Wc[64];
#pragma unroll
    for (int k = 0; k < 64; ++k) Wc[k] = W[k * 64 + l];
    float* row = lds[w];
    int g = blockIdx.x * 4 + w;
    const int G = GVB * 4;
    for (int t = g; t < NN / 8; t += G) {
        int n0 = t * 8;
#pragma unroll
        for (int r = 0; r < 8; ++r) row[r * 64 + l] = h[(size_t)(n0 + r) * 64 + l];
        __builtin_amdgcn_wave_barrier();
        float acc[8] = {0.f, 0.f, 0.f, 0.f, 0.f, 0.f, 0.f, 0.f};
#pragma unroll
        for (int k = 0; k < 64; k += 4) {
#pragma unroll
            for (int r = 0; r < 8; ++r) {
                float4 bv = *(const float4*)&row[r * 64 + k];
                acc[r] = fmaf(bv.x, Wc[k],     acc[r]);
                acc[r] = fmaf(bv.y, Wc[k + 1], acc[r]);
                acc[r] = fmaf(bv.z, Wc[k + 2], acc[r]);
                acc[r] = fmaf(bv.w, Wc[k + 3], acc[r]);
            }
        }
        __builtin_amdgcn_wave_barrier();
#pragma unroll
        for (int r = 0; r < 8; ++r)
            yh[(size_t)(n0 + r) * 64 + l] = __float2half(acc[r] * sk[n0 + r]);
    }
}

__global__ __launch_bounds__(256) void k_post_g(const float* __restrict__ zp,
                                                const float* __restrict__ W2,
                                                const float* __restrict__ b2,
                                                const float* __restrict__ gW,
                                                const int* __restrict__ roffs,
                                                const int* __restrict__ cnt,
                                                const float* __restrict__ keep,
                                                float* __restrict__ hOut,
                                                float* __restrict__ hwd,
                                                float* __restrict__ dinv, int mode) {
    __shared__ float lds[4][8 * 64];
    int tid = threadIdx.x, w = tid >> 6, l = tid & 63;
    float Wc[64];
#pragma unroll
    for (int k = 0; k < 64; ++k) Wc[k] = W2[k * 64 + l];
    float b2v = b2[l];
    float gWv = (mode < 3) ? gW[l] : 0.f;
    float* row = lds[w];
    int g = blockIdx.x * 4 + w;
    const int G = GVB * 4;
    for (int t = g; t < NN / 8; t += G) {
        int n0 = t * 8;
#pragma unroll
        for (int r = 0; r < 8; ++r) row[r * 64 + l] = zp[(size_t)(n0 + r) * 64 + l];
        __builtin_amdgcn_wave_barrier();
        float acc[8];
#pragma unroll
        for (int r = 0; r < 8; ++r) acc[r] = b2v;
#pragma unroll
        for (int k = 0; k < 64; k += 4) {
#pragma unroll
            for (int r = 0; r < 8; ++r) {
                float4 bv = *(const float4*)&row[r * 64 + k];
                acc[r] = fmaf(bv.x, Wc[k],     acc[r]);
                acc[r] = fmaf(bv.y, Wc[k + 1], acc[r]);
                acc[r] = fmaf(bv.z, Wc[k + 2], acc[r]);
                acc[r] = fmaf(bv.w, Wc[k + 3], acc[r]);
            }
        }
        __builtin_amdgcn_wave_barrier();
#pragma unroll
        for (int r = 0; r < 8; ++r) {
            acc[r] = fmaxf(acc[r], 0.f);
            hOut[(size_t)(n0 + r) * 64 + l] = acc[r];
        }
        if (mode < 3) {
#pragma unroll
            for (int r = 0; r < 8; ++r) {
                float t2 = acc[r] * gWv;
                for (int o = 32; o > 0; o >>= 1) t2 += __shfl_down(t2, o, 64);
                if (l == 0) {
                    int n = n0 + r;
                    float di;
                    if (mode == 1) di = 1.f / sqrtf((float)(roffs[n + 1] - roffs[n]) + 1.f);
                    else di = (keep[n] != 0.f) ? 1.f / sqrtf((float)cnt[n] + 1.f) : 0.f;
                    dinv[n] = di;
                    hwd[n] = t2 * di;
                }
            }
        }
    }
}

// ---------------- fp32 CSR gather (GIN1): 16 lanes/node, float4, unroll-4 -----------------
__global__ void k_gather_y(const float* __restrict__ y, const int* __restrict__ roffs,
                           const int* __restrict__ csrc, const float* __restrict__ b1,
                           float* __restrict__ z) {
    int tid = threadIdx.x;
    int d = blockIdx.x * 16 + (tid >> 4);
    int l = tid & 15;
    const float4* y4 = (const float4*)y;
    float4 acc = y4[(size_t)d * 16 + l];            // self term
    int e0 = roffs[d], e1 = roffs[d + 1];
    int e = e0;
    for (; e + 3 < e1; e += 4) {
        int s0 = csrc[e], s1 = csrc[e + 1], s2 = csrc[e + 2], s3 = csrc[e + 3];
        float4 v0 = y4[(size_t)s0 * 16 + l];
        float4 v1 = y4[(size_t)s1 * 16 + l];
        float4 v2 = y4[(size_t)s2 * 16 + l];
        float4 v3 = y4[(size_t)s3 * 16 + l];
        acc.x += (v0.x + v1.x) + (v2.x + v3.x);
        acc.y += (v0.y + v1.y) + (v2.y + v3.y);
        acc.z += (v0.z + v1.z) + (v2.z + v3.z);
        acc.w += (v0.w + v1.w) + (v2.w + v3.w);
    }
    for (; e < e1; ++e) {
        float4 v0 = y4[(size_t)csrc[e] * 16 + l];
        acc.x += v0.x; acc.y += v0.y; acc.z += v0.z; acc.w += v0.w;
    }
    float4 o;
    o.x = fmaxf(acc.x + b1[4 * l],     0.f);
    o.y = fmaxf(acc.y + b1[4 * l + 1], 0.f);
    o.z = fmaxf(acc.z + b1[4 * l + 2], 0.f);
    o.w = fmaxf(acc.w + b1[4 * l + 3], 0.f);
    ((float4*)z)[(size_t)d * 16 + l] = o;
}

// ---------------- fp16 CSR gather (GIN2/GIN3): 16 lanes/node, 8B loads, unroll-4 ----------
__global__ void k_gather_h(const __half* __restrict__ yh, const int* __restrict__ roffs,
                           const int* __restrict__ csrc, const float* __restrict__ keepd,
                           const float* __restrict__ sk, const float* __restrict__ b1,
                           float* __restrict__ z, int* __restrict__ cnt) {
    int tid = threadIdx.x;
    int d = blockIdx.x * 16 + (tid >> 4);
    int l = tid & 15;
    const float2* yv = (const float2*)yh;           // 8 B = 4 halves per load
    float2 raw = yv[(size_t)d * 16 + l];
    __half2 p0 = ((const __half2*)&raw)[0], p1 = ((const __half2*)&raw)[1];
    float4 acc = make_float4(__low2float(p0), __high2float(p0),
                             __low2float(p1), __high2float(p1));  // self term
    int c = 0;
    if (!keepd || keepd[d] != 0.f) {                // dst-side gate (group-uniform)
        int e0 = roffs[d], e1 = roffs[d + 1];
        int e = e0;
        for (; e + 3 < e1; e += 4) {
            int s0 = csrc[e], s1 = csrc[e + 1], s2 = csrc[e + 2], s3 = csrc[e + 3];
            float2 r0 = yv[(size_t)s0 * 16 + l];
            float2 r1 = yv[(size_t)s1 * 16 + l];
            float2 r2 = yv[(size_t)s2 * 16 + l];
            float2 r3 = yv[(size_t)s3 * 16 + l];
#pragma unroll
            for (int j = 0; j < 4; ++j) {
                float2 rr = (j == 0) ? r0 : (j == 1) ? r1 : (j == 2) ? r2 : r3;
                __half2 a0 = ((const __half2*)&rr)[0], a1 = ((const __half2*)&rr)[1];
                acc.x += __low2float(a0); acc.y += __high2float(a0);
                acc.z += __low2float(a1); acc.w += __high2float(a1);
            }
            if (sk) c += (sk[s0] > 0.f) + (sk[s1] > 0.f) + (sk[s2] > 0.f) + (sk[s3] > 0.f);
        }
        for (; e < e1; ++e) {
            int s0 = csrc[e];
            float2 rr = yv[(size_t)s0 * 16 + l];
            __half2 a0 = ((const __half2*)&rr)[0], a1 = ((const __half2*)&rr)[1];
            acc.x += __low2float(a0); acc.y += __high2float(a0);
            acc.z += __low2float(a1); acc.w += __high2float(a1);
            if (sk) c += (sk[s0] > 0.f);
        }
    }
    float4 o;
    o.x = fmaxf(acc.x + b1[4 * l],     0.f);
    o.y = fmaxf(acc.y + b1[4 * l + 1], 0.f);
    o.z = fmaxf(acc.z + b1[4 * l + 2], 0.f);
    o.w = fmaxf(acc.w + b1[4 * l + 3], 0.f);
    ((float4*)z)[(size_t)d * 16 + l] = o;
    if (cnt && l == 0) cnt[d] = c;
}

// ---------------- attention gather: attn[i] = dinv[i]*(sum_nbr hwd + hwd[i]) + gb ----------------
__global__ void k_attn(const int* __restrict__ roffs, const int* __restrict__ csrc,
                       const float* __restrict__ hwd, const float* __restrict__ dinv,
                       const float* __restrict__ gb, float* __restrict__ attn) {
    int i = blockIdx.x * 256 + threadIdx.x;
    if (i >= NN) return;
    float sum = hwd[i];
    int e0 = roffs[i], e1 = roffs[i + 1];
    for (int e = e0; e < e1; ++e) sum += hwd[csrc[e]];
    attn[i] = dinv[i] * sum + gb[0];
}

// ---------------- per-graph softmax + threshold; also emits sk = score*keep ----------------
__global__ void k_softmax_pool(const float* __restrict__ attn, const float* __restrict__ nmask,
                               const int* __restrict__ offs, float* __restrict__ score,
                               float* __restrict__ keep, float* __restrict__ sk) {
    int b = blockIdx.x, tid = threadIdx.x;
    int s0 = offs[b], s1 = offs[b + 1];
    __shared__ float red[256];
    float m = NEGF;
    for (int i = s0 + tid; i < s1; i += 256) {
        float nm = nmask ? nmask[i] : 1.f;
        if (nm > 0.f) m = fmaxf(m, attn[i]);
    }
    red[tid] = m; __syncthreads();
    for (int o = 128; o > 0; o >>= 1) { if (tid < o) red[tid] = fmaxf(red[tid], red[tid + o]); __syncthreads(); }
    m = red[0]; __syncthreads();
    float s = 0.f;
    for (int i = s0 + tid; i < s1; i += 256) {
        float nm = nmask ? nmask[i] : 1.f;
        if (nm > 0.f) s += expf(attn[i] - m);
    }
    red[tid] = s; __syncthreads();
    for (int o = 128; o > 0; o >>= 1) { if (tid < o) red[tid] += red[tid + o]; __syncthreads(); }
    s = red[0]; __syncthreads();
    float sden = fmaxf(s, 1e-30f);
    float smax = NEGF;
    for (int i = s0 + tid; i < s1; i += 256) {
        float nm = nmask ? nmask[i] : 1.f;
        float sc = (nm > 0.f) ? expf(attn[i] - m) / sden : 0.f;
        score[i] = sc;
        smax = fmaxf(smax, (nm > 0.f) ? sc : NEGF);
    }
    red[tid] = smax; __syncthreads();
    for (int o = 128; o > 0; o >>= 1) { if (tid < o) red[tid] = fmaxf(red[tid], red[tid + o]); __syncthreads(); }
    smax = red[0]; __syncthreads();
    float thr = fminf(1e-3f, smax - 1e-7f);
    for (int i = s0 + tid; i < s1; i += 256) {
        float nm = nmask ? nmask[i] : 1.f;
        float sc = score[i];
        float kp = (nm > 0.f && sc > thr) ? 1.f : 0.f;
        keep[i] = kp;
        sk[i] = sc * kp;
    }
}

// ---------------- output head ----------------
__global__ void k_gmax_linear(const float* __restrict__ h, const float* __restrict__ keep2,
                              const int* __restrict__ offs, const float* __restrict__ Wl,
                              const float* __restrict__ bl, float* __restrict__ out) {
    int b = blockIdx.x, tid = threadIdx.x;
    int s0 = offs[b], s1 = offs[b + 1];
    int f = tid & 63, g = tid >> 6;
    float m = NEGF;
    for (int i = s0 + g; i < s1; i += 4)
        if (keep2[i] > 0.f) m = fmaxf(m, h[(size_t)i * 64 + f]);
    __shared__ float red[256];
    red[tid] = m; __syncthreads();
    if (g == 0) {
        m = fmaxf(fmaxf(red[f], red[64 + f]), fmaxf(red[128 + f], red[192 + f]));
        float v = m * Wl[f];
        for (int o = 32; o > 0; o >>= 1) v += __shfl_down(v, o, 64);
        if (f == 0) out[b] = v + bl[0];
    }
}

// ---------------- prefix sum of keep1 (exact int) ----------------
__global__ void k_scan1(const float* __restrict__ keep1, int* __restrict__ prefix,
                        int* __restrict__ bsums) {
    int blk = blockIdx.x, tid = threadIdx.x;
    int base = blk * 1024;
    int vals[4], tsum = 0;
    for (int j = 0; j < 4; ++j) {
        int idx = base + tid * 4 + j;
        int v = (idx < NN && keep1[idx] > 0.f) ? 1 : 0;
        tsum += v; vals[j] = tsum;
    }
    __shared__ int sh[256];
    sh[tid] = tsum; __syncthreads();
    for (int o = 1; o < 256; o <<= 1) {
        int v = (tid >= o) ? sh[tid - o] : 0;
        __syncthreads();
        sh[tid] += v;
        __syncthreads();
    }
    int excl = sh[tid] - tsum;
    for (int j = 0; j < 4; ++j) {
        int idx = base + tid * 4 + j;
        if (idx < NN) prefix[idx] = excl + vals[j];
    }
    if (tid == 255) bsums[blk] = sh[255];
}
// add prefix of raw block sums (inline reduce; block covers one 1024-elem scan-block)
__global__ void k_scan3(int* __restrict__ prefix, const int* __restrict__ bsums) {
    __shared__ int sh[256];
    int t = threadIdx.x;
    int sb = blockIdx.x >> 2;
    sh[t] = (t < sb) ? bsums[t] : 0;
    __syncthreads();
    for (int o = 128; o > 0; o >>= 1) { if (t < o) sh[t] += sh[t + o]; __syncthreads(); }
    int pre = sh[0];
    int idx = blockIdx.x * 256 + t;
    if (idx < NN) prefix[idx] += pre;
}

// ---------------- attention KL loss + ratio ----------------
__global__ void k_kl(const float* __restrict__ score2, const float* __restrict__ keep2,
                     const int* __restrict__ prefix, const float* __restrict__ natt,
                     const int* __restrict__ offs, float* __restrict__ out_loss,
                     float* __restrict__ c_total) {
    int b = blockIdx.x, tid = threadIdx.x;
    int s0 = offs[b], s1 = offs[b + 1];
    float s = 0.f, c = 0.f;
    for (int i = s0 + tid; i < s1; i += 256) {
        if (keep2[i] > 0.f) {
            int r1 = prefix[i] - 1;
            r1 = max(0, min(r1, NN - 1));
            float t = natt[r1];
            float logp = logf(score2[i] + 1e-14f);
            float kl = ((t > 0.f) ? t * logf(fmaxf(t, 1e-38f)) : 0.f) - t * logp;
            s += kl; c += 1.f;
        }
    }
    __shared__ float rs[256], rc[256];
    rs[tid] = s; rc[tid] = c; __syncthreads();
    for (int o = 128; o > 0; o >>= 1) {
        if (tid < o) { rs[tid] += rs[tid + o]; rc[tid] += rc[tid + o]; }
        __syncthreads();
    }
    if (tid == 0) {
        out_loss[b] = rs[0] / fmaxf(rc[0], 1.f);
        atomicAdd(c_total, rc[0]);
    }
}
__global__ void k_final(const float* __restrict__ c_total, float* __restrict__ out) {
    out[0] = c_total[0] / (float)NN;
}

extern "C" void kernel_launch(void* const* d_in, const int* in_sizes, int n_in,
                              void* d_out, int out_size, void* d_ws, size_t ws_size,
                              hipStream_t stream) {
    const float* x    = (const float*)d_in[0];
    const int*   src  = (const int*)d_in[1];
    const int*   dst  = (const int*)d_in[2];
    const int*   batch= (const int*)d_in[3];
    const float* natt = (const float*)d_in[4];
    const float* W11 = (const float*)d_in[5],  *b11 = (const float*)d_in[6];
    const float* W12 = (const float*)d_in[7],  *b12 = (const float*)d_in[8];
    const float* gW1 = (const float*)d_in[9],  *gb1 = (const float*)d_in[10];
    const float* W21 = (const float*)d_in[11], *b21 = (const float*)d_in[12];
    const float* W22 = (const float*)d_in[13], *b22 = (const float*)d_in[14];
    const float* gW2 = (const float*)d_in[15], *gb2 = (const float*)d_in[16];
    const float* W31 = (const float*)d_in[17], *b31 = (const float*)d_in[18];
    const float* W32 = (const float*)d_in[19], *b32 = (const float*)d_in[20];
    const float* Wl  = (const float*)d_in[21], *bl  = (const float*)d_in[22];
    float* out = (float*)d_out;

    // workspace layout
    float* hA     = (float*)d_ws;                 // N*64  (reused as h3)
    float* hB     = hA + (size_t)NN * 64;         // N*64
    float* ybuf   = hB + (size_t)NN * 64;         // N*64  (CSR build: H/Hs; fp16 y aliases)
    float* zbuf   = ybuf + (size_t)NN * 64;       // N*64  (CSR build: ebuf aliases)
    float* hwd    = zbuf + (size_t)NN * 64;       // N
    float* dinv   = hwd + NN;                     // N
    float* attn   = dinv + NN;                    // N
    float* score1 = attn + NN;                    // N
    float* keep1  = score1 + NN;                  // N
    float* sk1    = keep1 + NN;                   // N
    float* score2 = sk1 + NN;                     // N
    float* keep2  = score2 + NN;                  // N
    float* sk2    = keep2 + NN;                   // N
    int*   prefix = (int*)(sk2 + NN);             // N
    int*   cnt    = prefix + NN;                  // N
    int*   roffs  = cnt + NN;                     // N+1
    int*   csrc   = roffs + NN + 1;               // E
    int*   offs   = csrc + NE;                    // B+1
    int*   bsums  = offs + NB + 1;                // 128
    float* c_total= (float*)(bsums + 128);        // 1
    // CSR-build scratch aliases (dead regions during build)
    int*   H      = (int*)ybuf;                   // NBKT*P_SORT
    int*   Hs     = H + HLEN;                     // NBKT*P_SORT
    int2*  ebuf   = (int2*)zbuf;                  // E pairs (12.8 MB <= 25.6 MB region)
    __half* yh    = (__half*)ybuf;                // fp16 y for GIN2/3

    const int nblk_n   = (NN + 255) / 256;
    const int nblk_n16 = NN / 16;

    // CSR by dst: coarse hist (+graph offs) -> scan -> pair scatter -> per-bucket LDS CSR
    k_hist_coarse<<<P_SORT, 256, 0, stream>>>(dst, batch, offs, H);
    k_iscan_blk<<<HSCAN_BLK, 256, 0, stream>>>(H, Hs, bsums, HLEN);
    k_iscan_add<<<(HLEN + 255) / 256, 256, 0, stream>>>(Hs, bsums, HLEN);
    k_scatter_pairs<<<P_SORT, 256, 0, stream>>>(src, dst, Hs, ebuf);
    k_bucket_csr<<<NBKT, 256, 0, stream>>>(ebuf, Hs, roffs, csrc);

    // ---- GIN1: pre-GEMM (fp32) + gather (fp32, +relu/bias) + post ----
    k_pre1_g<<<GVB, 256, 0, stream>>>(x, W11, ybuf);
    k_gather_y<<<nblk_n16, 256, 0, stream>>>(ybuf, roffs, csrc, b11, zbuf);
    k_post_g<<<GVB, 256, 0, stream>>>(zbuf, W12, b12, gW1, roffs, nullptr, nullptr,
                                      hA, hwd, dinv, 1);
    k_attn<<<nblk_n, 256, 0, stream>>>(roffs, csrc, hwd, dinv, gb1, attn);
    k_softmax_pool<<<NB, 256, 0, stream>>>(attn, nullptr, offs, score1, keep1, sk1);

    // ---- GIN2 (fp16 gather payload) ----
    k_pre23_h<<<GVB, 256, 0, stream>>>(hA, sk1, W21, yh);
    k_gather_h<<<nblk_n16, 256, 0, stream>>>(yh, roffs, csrc, keep1, sk1, b21, zbuf, cnt);
    k_post_g<<<GVB, 256, 0, stream>>>(zbuf, W22, b22, gW2, roffs, cnt, keep1,
                                      hB, hwd, dinv, 2);
    k_attn<<<nblk_n, 256, 0, stream>>>(roffs, csrc, hwd, dinv, gb2, attn);
    k_softmax_pool<<<NB, 256, 0, stream>>>(attn, keep1, offs, score2, keep2, sk2);

    // ---- GIN3 (fp16 gather payload; h3 written into hA buffer) ----
    k_pre23_h<<<GVB, 256, 0, stream>>>(hB, sk2, W31, yh);
    k_gather_h<<<nblk_n16, 256, 0, stream>>>(yh, roffs, csrc, keep2, nullptr, b31, zbuf, nullptr);
    k_post_g<<<GVB, 256, 0, stream>>>(zbuf, W32, b32, nullptr, roffs, nullptr, nullptr,
                                      hA, nullptr, nullptr, 3);

    // ---- head: global max pool + linear ----
    k_gmax_linear<<<NB, 256, 0, stream>>>(hA, keep2, offs, Wl, bl, out);

    // ---- attention KL loss + ratio ----
    k_scan1<<<NSCAN_BLK, 256, 0, stream>>>(keep1, prefix, bsums);
    k_scan3<<<nblk_n, 256, 0, stream>>>(prefix, bsums);
    hipMemsetAsync(c_total, 0, sizeof(float), stream);
    k_kl<<<NB, 256, 0, stream>>>(score2, keep2, prefix, natt, offs, out + NB, c_total);
    k_final<<<1, 1, 0, stream>>>(c_total, out + 2 * NB);
}

// Round 14
// 508.017 us; speedup vs baseline: 1.1761x; 1.0003x over previous
//
#include <hip/hip_runtime.h>
#include <hip/hip_fp16.h>
#include <math.h>

#define NN 100000
#define NE 1600000
#define NB 256
#define NEGF (-1e30f)
#define NSCAN_BLK ((NN + 1023) / 1024)
#define GVB 1024            // grid-stride GEMV blocks
#define P_SORT 256          // blocks in coarse histogram/scatter
#define NBKT 391            // ceil(NN/256) coarse buckets (dst>>8)
#define HLEN (NBKT * P_SORT)
#define HSCAN_BLK ((HLEN + 1023) / 1024)
#define BKT_CAP 6144        // LDS staging ints (24 KB); avg bucket = 4096 edges
#define NMASKW 1566         // ull words for 100k keep bits

// ---------------- CSR build: two-level counting sort ----------------
__global__ void k_hist_coarse(const int* __restrict__ dst, const int* __restrict__ batch,
                              int* __restrict__ offs, int* __restrict__ H) {
    __shared__ int lh[NBKT];
    int p = blockIdx.x, tid = threadIdx.x;
    if (p == 0) {
        for (int g = tid; g <= NB; g += 256) {
            int lo = 0, hi = NN;
            while (lo < hi) { int mid = (lo + hi) >> 1; if (batch[mid] < g) lo = mid + 1; else hi = mid; }
            offs[g] = lo;
        }
    }
    for (int i = tid; i < NBKT; i += 256) lh[i] = 0;
    __syncthreads();
    int c0 = p * (NE / P_SORT), c1 = c0 + NE / P_SORT;
    for (int i = c0 + tid; i < c1; i += 256) atomicAdd(&lh[dst[i] >> 8], 1);
    __syncthreads();
    for (int i = tid; i < NBKT; i += 256) H[i * P_SORT + p] = lh[i];
}
__global__ void k_iscan_blk(const int* __restrict__ in, int* __restrict__ pref,
                            int* __restrict__ bsums, int len) {
    int blk = blockIdx.x, tid = threadIdx.x;
    int base = blk * 1024;
    int vals[4], tsum = 0;
    for (int j = 0; j < 4; ++j) {
        int idx = base + tid * 4 + j;
        int v = (idx < len) ? in[idx] : 0;
        vals[j] = tsum; tsum += v;               // exclusive within thread
    }
    __shared__ int sh[256];
    sh[tid] = tsum; __syncthreads();
    for (int o = 1; o < 256; o <<= 1) {
        int v = (tid >= o) ? sh[tid - o] : 0;
        __syncthreads();
        sh[tid] += v;
        __syncthreads();
    }
    int excl = sh[tid] - tsum;
    for (int j = 0; j < 4; ++j) {
        int idx = base + tid * 4 + j;
        if (idx < len) pref[idx] = excl + vals[j];
    }
    if (tid == 255) bsums[blk] = sh[255];
}
// adds prefix of raw block sums (inline reduce; block covers 256 idx of one scan-block)
__global__ void k_iscan_add(int* __restrict__ pref, const int* __restrict__ bsums, int len) {
    __shared__ int sh[256];
    int t = threadIdx.x;
    int sb = blockIdx.x >> 2;                     // 1024-elem scan-block index
    sh[t] = (t < sb) ? bsums[t] : 0;
    __syncthreads();
    for (int o = 128; o > 0; o >>= 1) { if (t < o) sh[t] += sh[t + o]; __syncthreads(); }
    int pre = sh[0];
    int idx = blockIdx.x * 256 + t;
    if (idx < len) pref[idx] += pre;
}
__global__ void k_scatter_pairs(const int* __restrict__ src, const int* __restrict__ dst,
                                const int* __restrict__ Hs, int2* __restrict__ ebuf) {
    __shared__ int curs[NBKT];
    int p = blockIdx.x, tid = threadIdx.x;
    for (int i = tid; i < NBKT; i += 256) curs[i] = Hs[i * P_SORT + p];
    __syncthreads();
    int c0 = p * (NE / P_SORT), c1 = c0 + NE / P_SORT;
    for (int i = c0 + tid; i < c1; i += 256) {
        int d = dst[i];
        int pos = atomicAdd(&curs[d >> 8], 1);
        ebuf[pos] = make_int2(src[i], d);
    }
}
__global__ void k_bucket_csr(const int2* __restrict__ ebuf, const int* __restrict__ Hs,
                             int* __restrict__ roffs, int* __restrict__ csrc) {
    __shared__ int hist2[256];
    __shared__ int curs2[256];
    __shared__ int sh[256];
    __shared__ int stage[BKT_CAP];
    int b = blockIdx.x, tid = threadIdx.x;
    int e0 = Hs[b * P_SORT];
    int e1 = (b + 1 < NBKT) ? Hs[(b + 1) * P_SORT] : NE;
    int n0 = b * 256;
    int cntb = e1 - e0;
    if (b == 0 && tid == 0) roffs[NN] = NE;
    hist2[tid] = 0;
    __syncthreads();
    for (int i = e0 + tid; i < e1; i += 256) atomicAdd(&hist2[ebuf[i].y & 255], 1);
    __syncthreads();
    int v = hist2[tid];
    sh[tid] = v; __syncthreads();
    for (int o = 1; o < 256; o <<= 1) {
        int u = (tid >= o) ? sh[tid - o] : 0;
        __syncthreads();
        sh[tid] += u;
        __syncthreads();
    }
    int excl = sh[tid] - v;
    int node = n0 + tid;
    if (node < NN) roffs[node] = e0 + excl;
    curs2[tid] = excl;
    __syncthreads();
    if (cntb <= BKT_CAP) {
        for (int i = e0 + tid; i < e1; i += 256) {
            int2 pr = ebuf[i];
            int pos = atomicAdd(&curs2[pr.y & 255], 1);
            stage[pos] = pr.x;
        }
        __syncthreads();
        for (int i = tid; i < cntb; i += 256) csrc[e0 + i] = stage[i];
    } else {
        for (int i = e0 + tid; i < e1; i += 256) {
            int2 pr = ebuf[i];
            int pos = atomicAdd(&curs2[pr.y & 255], 1);
            csrc[e0 + pos] = pr.x;
        }
    }
}

// ---------------- GEMV kernels: W in VGPRs, broadcast via wave-local LDS ds_read_b128 -----
__global__ __launch_bounds__(256) void k_pre1_g(const float* __restrict__ x,
                                                const float* __restrict__ W,
                                                float* __restrict__ y) {
    __shared__ float lds[4][4 * 128];
    int tid = threadIdx.x, w = tid >> 6, l = tid & 63;
    float Wc[128];
#pragma unroll
    for (int k = 0; k < 128; ++k) Wc[k] = W[k * 64 + l];
    float* row = lds[w];
    int g = blockIdx.x * 4 + w;
    const int G = GVB * 4;
    for (int t = g; t < NN / 4; t += G) {
        int n0 = t * 4;
#pragma unroll
        for (int r = 0; r < 4; ++r) {
            row[r * 128 + l]      = x[(size_t)(n0 + r) * 128 + l];
            row[r * 128 + 64 + l] = x[(size_t)(n0 + r) * 128 + 64 + l];
        }
        __builtin_amdgcn_wave_barrier();
        float acc[4] = {0.f, 0.f, 0.f, 0.f};
#pragma unroll
        for (int k = 0; k < 128; k += 4) {
#pragma unroll
            for (int r = 0; r < 4; ++r) {
                float4 bv = *(const float4*)&row[r * 128 + k];   // uniform addr -> LDS broadcast
                acc[r] = fmaf(bv.x, Wc[k],     acc[r]);
                acc[r] = fmaf(bv.y, Wc[k + 1], acc[r]);
                acc[r] = fmaf(bv.z, Wc[k + 2], acc[r]);
                acc[r] = fmaf(bv.w, Wc[k + 3], acc[r]);
            }
        }
        __builtin_amdgcn_wave_barrier();
#pragma unroll
        for (int r = 0; r < 4; ++r) y[(size_t)(n0 + r) * 64 + l] = acc[r];
    }
}

__global__ __launch_bounds__(256) void k_pre23_h(const float* __restrict__ h,
                                                 const float* __restrict__ sk,
                                                 const float* __restrict__ W,
                                                 __half* __restrict__ yh) {
    __shared__ float lds[4][8 * 64];
    int tid = threadIdx.x, w = tid >> 6, l = tid & 63;
    float Wc[64];
#pragma unroll
    for (int k = 0; k < 64; ++k) Wc[k] = W[k * 64 + l];
    float* row = lds[w];
    int g = blockIdx.x * 4 + w;
    const int G = GVB * 4;
    for (int t = g; t < NN / 8; t += G) {
        int n0 = t * 8;
#pragma unroll
        for (int r = 0; r < 8; ++r) row[r * 64 + l] = h[(size_t)(n0 + r) * 64 + l];
        __builtin_amdgcn_wave_barrier();
        float acc[8] = {0.f, 0.f, 0.f, 0.f, 0.f, 0.f, 0.f, 0.f};
#pragma unroll
        for (int k = 0; k < 64; k += 4) {
#pragma unroll
            for (int r = 0; r < 8; ++r) {
                float4 bv = *(const float4*)&row[r * 64 + k];
                acc[r] = fmaf(bv.x, Wc[k],     acc[r]);
                acc[r] = fmaf(bv.y, Wc[k + 1], acc[r]);
                acc[r] = fmaf(bv.z, Wc[k + 2], acc[r]);
                acc[r] = fmaf(bv.w, Wc[k + 3], acc[r]);
            }
        }
        __builtin_amdgcn_wave_barrier();
#pragma unroll
        for (int r = 0; r < 8; ++r)
            yh[(size_t)(n0 + r) * 64 + l] = __float2half(acc[r] * sk[n0 + r]);
    }
}

__global__ __launch_bounds__(256) void k_post_g(const float* __restrict__ zp,
                                                const float* __restrict__ W2,
                                                const float* __restrict__ b2,
                                                const float* __restrict__ gW,
                                                const int* __restrict__ roffs,
                                                const int* __restrict__ cnt,
                                                const float* __restrict__ keep,
                                                float* __restrict__ hOut,
                                                float* __restrict__ hwd,
                                                float* __restrict__ dinv, int mode) {
    __shared__ float lds[4][8 * 64];
    int tid = threadIdx.x, w = tid >> 6, l = tid & 63;
    float Wc[64];
#pragma unroll
    for (int k = 0; k < 64; ++k) Wc[k] = W2[k * 64 + l];
    float b2v = b2[l];
    float gWv = (mode < 3) ? gW[l] : 0.f;
    float* row = lds[w];
    int g = blockIdx.x * 4 + w;
    const int G = GVB * 4;
    for (int t = g; t < NN / 8; t += G) {
        int n0 = t * 8;
#pragma unroll
        for (int r = 0; r < 8; ++r) row[r * 64 + l] = zp[(size_t)(n0 + r) * 64 + l];
        __builtin_amdgcn_wave_barrier();
        float acc[8];
#pragma unroll
        for (int r = 0; r < 8; ++r) acc[r] = b2v;
#pragma unroll
        for (int k = 0; k < 64; k += 4) {
#pragma unroll
            for (int r = 0; r < 8; ++r) {
                float4 bv = *(const float4*)&row[r * 64 + k];
                acc[r] = fmaf(bv.x, Wc[k],     acc[r]);
                acc[r] = fmaf(bv.y, Wc[k + 1], acc[r]);
                acc[r] = fmaf(bv.z, Wc[k + 2], acc[r]);
                acc[r] = fmaf(bv.w, Wc[k + 3], acc[r]);
            }
        }
        __builtin_amdgcn_wave_barrier();
#pragma unroll
        for (int r = 0; r < 8; ++r) {
            acc[r] = fmaxf(acc[r], 0.f);
            hOut[(size_t)(n0 + r) * 64 + l] = acc[r];
        }
        if (mode < 3) {
#pragma unroll
            for (int r = 0; r < 8; ++r) {
                float t2 = acc[r] * gWv;
                for (int o = 32; o > 0; o >>= 1) t2 += __shfl_down(t2, o, 64);
                if (l == 0) {
                    int n = n0 + r;
                    float di;
                    if (mode == 1) di = 1.f / sqrtf((float)(roffs[n + 1] - roffs[n]) + 1.f);
                    else di = (keep[n] != 0.f) ? 1.f / sqrtf((float)cnt[n] + 1.f) : 0.f;
                    dinv[n] = di;
                    hwd[n] = t2 * di;
                }
            }
        }
    }
}

// ---------------- fp32 CSR gather (GIN1): 16 lanes/node, float4, unroll-4 -----------------
__global__ void k_gather_y(const float* __restrict__ y, const int* __restrict__ roffs,
                           const int* __restrict__ csrc, const float* __restrict__ b1,
                           float* __restrict__ z) {
    int tid = threadIdx.x;
    int d = blockIdx.x * 16 + (tid >> 4);
    int l = tid & 15;
    const float4* y4 = (const float4*)y;
    float4 acc = y4[(size_t)d * 16 + l];            // self term
    int e0 = roffs[d], e1 = roffs[d + 1];
    int e = e0;
    for (; e + 3 < e1; e += 4) {
        int s0 = csrc[e], s1 = csrc[e + 1], s2 = csrc[e + 2], s3 = csrc[e + 3];
        float4 v0 = y4[(size_t)s0 * 16 + l];
        float4 v1 = y4[(size_t)s1 * 16 + l];
        float4 v2 = y4[(size_t)s2 * 16 + l];
        float4 v3 = y4[(size_t)s3 * 16 + l];
        acc.x += (v0.x + v1.x) + (v2.x + v3.x);
        acc.y += (v0.y + v1.y) + (v2.y + v3.y);
        acc.z += (v0.z + v1.z) + (v2.z + v3.z);
        acc.w += (v0.w + v1.w) + (v2.w + v3.w);
    }
    for (; e < e1; ++e) {
        float4 v0 = y4[(size_t)csrc[e] * 16 + l];
        acc.x += v0.x; acc.y += v0.y; acc.z += v0.z; acc.w += v0.w;
    }
    float4 o;
    o.x = fmaxf(acc.x + b1[4 * l],     0.f);
    o.y = fmaxf(acc.y + b1[4 * l + 1], 0.f);
    o.z = fmaxf(acc.z + b1[4 * l + 2], 0.f);
    o.w = fmaxf(acc.w + b1[4 * l + 3], 0.f);
    ((float4*)z)[(size_t)d * 16 + l] = o;
}

// ---------------- fp16 CSR gather (GIN2/GIN3): 16 lanes/node; keep-bitmask gate/count -----
__global__ void k_gather_h(const __half* __restrict__ yh, const int* __restrict__ roffs,
                           const int* __restrict__ csrc,
                           const unsigned long long* __restrict__ kmask,
                           const float* __restrict__ b1,
                           float* __restrict__ z, int* __restrict__ cnt) {
    int tid = threadIdx.x;
    int d = blockIdx.x * 16 + (tid >> 4);
    int l = tid & 15;
    const float2* yv = (const float2*)yh;           // 8 B = 4 halves per load
    float2 raw = yv[(size_t)d * 16 + l];
    __half2 p0 = ((const __half2*)&raw)[0], p1 = ((const __half2*)&raw)[1];
    float4 acc = make_float4(__low2float(p0), __high2float(p0),
                             __low2float(p1), __high2float(p1));  // self term
    int c = 0;
    if ((kmask[d >> 6] >> (d & 63)) & 1ull) {       // dst-side gate (group-uniform)
        int e0 = roffs[d], e1 = roffs[d + 1];
        int e = e0;
        for (; e + 3 < e1; e += 4) {
            int s0 = csrc[e], s1 = csrc[e + 1], s2 = csrc[e + 2], s3 = csrc[e + 3];
            float2 r0 = yv[(size_t)s0 * 16 + l];
            float2 r1 = yv[(size_t)s1 * 16 + l];
            float2 r2 = yv[(size_t)s2 * 16 + l];
            float2 r3 = yv[(size_t)s3 * 16 + l];
#pragma unroll
            for (int j = 0; j < 4; ++j) {
                float2 rr = (j == 0) ? r0 : (j == 1) ? r1 : (j == 2) ? r2 : r3;
                __half2 a0 = ((const __half2*)&rr)[0], a1 = ((const __half2*)&rr)[1];
                acc.x += __low2float(a0); acc.y += __high2float(a0);
                acc.z += __low2float(a1); acc.w += __high2float(a1);
            }
            if (cnt) c += (int)((kmask[s0 >> 6] >> (s0 & 63)) & 1ull)
                        + (int)((kmask[s1 >> 6] >> (s1 & 63)) & 1ull)
                        + (int)((kmask[s2 >> 6] >> (s2 & 63)) & 1ull)
                        + (int)((kmask[s3 >> 6] >> (s3 & 63)) & 1ull);
        }
        for (; e < e1; ++e) {
            int s0 = csrc[e];
            float2 rr = yv[(size_t)s0 * 16 + l];
            __half2 a0 = ((const __half2*)&rr)[0], a1 = ((const __half2*)&rr)[1];
            acc.x += __low2float(a0); acc.y += __high2float(a0);
            acc.z += __low2float(a1); acc.w += __high2float(a1);
            if (cnt) c += (int)((kmask[s0 >> 6] >> (s0 & 63)) & 1ull);
        }
    }
    float4 o;
    o.x = fmaxf(acc.x + b1[4 * l],     0.f);
    o.y = fmaxf(acc.y + b1[4 * l + 1], 0.f);
    o.z = fmaxf(acc.z + b1[4 * l + 2], 0.f);
    o.w = fmaxf(acc.w + b1[4 * l + 3], 0.f);
    ((float4*)z)[(size_t)d * 16 + l] = o;
    if (cnt && l == 0) cnt[d] = c;
}

// ---------------- fused pool: per-graph attn (LDS) + softmax + threshold + sk -------------
__global__ void k_pool(const int* __restrict__ roffs, const int* __restrict__ csrc,
                       const float* __restrict__ hwd, const float* __restrict__ dinv,
                       const float* __restrict__ gb, const float* __restrict__ nmask,
                       const int* __restrict__ offs, float* __restrict__ score,
                       float* __restrict__ keep, float* __restrict__ sk) {
    __shared__ float attn_s[2048];
    __shared__ float red[256];
    int b = blockIdx.x, tid = threadIdx.x;
    int s0 = offs[b], s1 = offs[b + 1];
    int len = s1 - s0;
    float gbv = gb[0];
    for (int j = tid; j < len; j += 256) {
        int i = s0 + j;
        float a = NEGF;
        if (!nmask || nmask[i] > 0.f) {             // skip edge work for dropped nodes
            float sum = hwd[i];
            int e0 = roffs[i], e1 = roffs[i + 1];
            for (int e = e0; e < e1; ++e) sum += hwd[csrc[e]];
            a = dinv[i] * sum + gbv;
        }
        attn_s[j] = a;
    }
    __syncthreads();
    float m = NEGF;
    for (int j = tid; j < len; j += 256) m = fmaxf(m, attn_s[j]);
    red[tid] = m; __syncthreads();
    for (int o = 128; o > 0; o >>= 1) { if (tid < o) red[tid] = fmaxf(red[tid], red[tid + o]); __syncthreads(); }
    m = red[0]; __syncthreads();
    float s = 0.f;
    for (int j = tid; j < len; j += 256) {
        float a = attn_s[j];
        if (a > 0.5f * NEGF) s += expf(a - m);
    }
    red[tid] = s; __syncthreads();
    for (int o = 128; o > 0; o >>= 1) { if (tid < o) red[tid] += red[tid + o]; __syncthreads(); }
    s = red[0]; __syncthreads();
    float sden = fmaxf(s, 1e-30f);
    float smax = NEGF;
    for (int j = tid; j < len; j += 256) {
        float a = attn_s[j];
        float sc = (a > 0.5f * NEGF) ? expf(a - m) / sden : 0.f;
        score[s0 + j] = sc;
        attn_s[j] = sc;                              // reuse LDS: now holds scores
        smax = fmaxf(smax, (a > 0.5f * NEGF) ? sc : NEGF);
    }
    red[tid] = smax; __syncthreads();
    for (int o = 128; o > 0; o >>= 1) { if (tid < o) red[tid] = fmaxf(red[tid], red[tid + o]); __syncthreads(); }
    smax = red[0]; __syncthreads();
    float thr = fminf(1e-3f, smax - 1e-7f);          // thr > 0, so dropped (sc=0) never pass
    for (int j = tid; j < len; j += 256) {
        float sc = attn_s[j];
        float kp = (sc > thr) ? 1.f : 0.f;
        keep[s0 + j] = kp;
        sk[s0 + j] = sc * kp;
    }
}

// ---------------- pack keep -> bitmask via ballot ----------------
__global__ void k_pack(const float* __restrict__ keep, unsigned long long* __restrict__ mask) {
    int i = blockIdx.x * 256 + threadIdx.x;
    float v = (i < NN) ? keep[i] : 0.f;
    unsigned long long m = __ballot(v > 0.f);
    if ((threadIdx.x & 63) == 0) mask[(unsigned)i >> 6] = m;
}

// ---------------- fused tail: global max pool + linear + KL loss ----------------
__global__ void k_tail(const float* __restrict__ h, const float* __restrict__ keep2,
                       const int* __restrict__ offs, const float* __restrict__ Wl,
                       const float* __restrict__ bl, const float* __restrict__ score2,
                       const int* __restrict__ prefix, const float* __restrict__ natt,
                       float* __restrict__ out, float* __restrict__ out_loss,
                       float* __restrict__ c_total) {
    int b = blockIdx.x, tid = threadIdx.x;
    int s0 = offs[b], s1 = offs[b + 1];
    int f = tid & 63, g = tid >> 6;
    float m = NEGF;
    for (int i = s0 + g; i < s1; i += 4)
        if (keep2[i] > 0.f) m = fmaxf(m, h[(size_t)i * 64 + f]);
    __shared__ float red[256];
    red[tid] = m; __syncthreads();
    if (g == 0) {
        m = fmaxf(fmaxf(red[f], red[64 + f]), fmaxf(red[128 + f], red[192 + f]));
        float v = m * Wl[f];
        for (int o = 32; o > 0; o >>= 1) v += __shfl_down(v, o, 64);
        if (f == 0) out[b] = v + bl[0];
    }
    __syncthreads();
    float ssum = 0.f, c = 0.f;
    for (int i = s0 + tid; i < s1; i += 256) {
        if (keep2[i] > 0.f) {
            int r1 = prefix[i] - 1;
            r1 = max(0, min(r1, NN - 1));
            float t = natt[r1];
            float logp = logf(score2[i] + 1e-14f);
            float kl = ((t > 0.f) ? t * logf(fmaxf(t, 1e-38f)) : 0.f) - t * logp;
            ssum += kl; c += 1.f;
        }
    }
    __shared__ float rs[256], rc[256];
    rs[tid] = ssum; rc[tid] = c; __syncthreads();
    for (int o = 128; o > 0; o >>= 1) {
        if (tid < o) { rs[tid] += rs[tid + o]; rc[tid] += rc[tid + o]; }
        __syncthreads();
    }
    if (tid == 0) {
        out_loss[b] = rs[0] / fmaxf(rc[0], 1.f);
        atomicAdd(c_total, rc[0]);
    }
}

// ---------------- prefix sum of keep1 (exact int) ----------------
__global__ void k_scan1(const float* __restrict__ keep1, int* __restrict__ prefix,
                        int* __restrict__ bsums) {
    int blk = blockIdx.x, tid = threadIdx.x;
    int base = blk * 1024;
    int vals[4], tsum = 0;
    for (int j = 0; j < 4; ++j) {
        int idx = base + tid * 4 + j;
        int v = (idx < NN && keep1[idx] > 0.f) ? 1 : 0;
        tsum += v; vals[j] = tsum;
    }
    __shared__ int sh[256];
    sh[tid] = tsum; __syncthreads();
    for (int o = 1; o < 256; o <<= 1) {
        int v = (tid >= o) ? sh[tid - o] : 0;
        __syncthreads();
        sh[tid] += v;
        __syncthreads();
    }
    int excl = sh[tid] - tsum;
    for (int j = 0; j < 4; ++j) {
        int idx = base + tid * 4 + j;
        if (idx < NN) prefix[idx] = excl + vals[j];
    }
    if (tid == 255) bsums[blk] = sh[255];
}
__global__ void k_scan3(int* __restrict__ prefix, const int* __restrict__ bsums) {
    __shared__ int sh[256];
    int t = threadIdx.x;
    int sb = blockIdx.x >> 2;
    sh[t] = (t < sb) ? bsums[t] : 0;
    __syncthreads();
    for (int o = 128; o > 0; o >>= 1) { if (t < o) sh[t] += sh[t + o]; __syncthreads(); }
    int pre = sh[0];
    int idx = blockIdx.x * 256 + t;
    if (idx < NN) prefix[idx] += pre;
}

__global__ void k_final(const float* __restrict__ c_total, float* __restrict__ out) {
    out[0] = c_total[0] / (float)NN;
}

extern "C" void kernel_launch(void* const* d_in, const int* in_sizes, int n_in,
                              void* d_out, int out_size, void* d_ws, size_t ws_size,
                              hipStream_t stream) {
    const float* x    = (const float*)d_in[0];
    const int*   src  = (const int*)d_in[1];
    const int*   dst  = (const int*)d_in[2];
    const int*   batch= (const int*)d_in[3];
    const float* natt = (const float*)d_in[4];
    const float* W11 = (const float*)d_in[5],  *b11 = (const float*)d_in[6];
    const float* W12 = (const float*)d_in[7],  *b12 = (const float*)d_in[8];
    const float* gW1 = (const float*)d_in[9],  *gb1 = (const float*)d_in[10];
    const float* W21 = (const float*)d_in[11], *b21 = (const float*)d_in[12];
    const float* W22 = (const float*)d_in[13], *b22 = (const float*)d_in[14];
    const float* gW2 = (const float*)d_in[15], *gb2 = (const float*)d_in[16];
    const float* W31 = (const float*)d_in[17], *b31 = (const float*)d_in[18];
    const float* W32 = (const float*)d_in[19], *b32 = (const float*)d_in[20];
    const float* Wl  = (const float*)d_in[21], *bl  = (const float*)d_in[22];
    float* out = (float*)d_out;

    // workspace layout
    float* hA     = (float*)d_ws;                 // N*64  (reused as h3)
    float* hB     = hA + (size_t)NN * 64;         // N*64
    float* ybuf   = hB + (size_t)NN * 64;         // N*64  (CSR build: H/Hs; fp16 y aliases)
    float* zbuf   = ybuf + (size_t)NN * 64;       // N*64  (CSR build: ebuf aliases)
    float* hwd    = zbuf + (size_t)NN * 64;       // N
    float* dinv   = hwd + NN;                     // N
    float* score1 = dinv + NN;                    // N
    float* keep1  = score1 + NN;                  // N
    float* sk1    = keep1 + NN;                   // N
    float* score2 = sk1 + NN;                     // N
    float* keep2  = score2 + NN;                  // N
    float* sk2    = keep2 + NN;                   // N
    int*   prefix = (int*)(sk2 + NN);             // N
    int*   cnt    = prefix + NN;                  // N
    int*   roffs  = cnt + NN;                     // N+1
    int*   csrc   = roffs + NN + 1;               // E
    int*   offs   = csrc + NE;                    // B+1
    int*   bsums  = offs + NB + 1;                // 128
    float* c_total= (float*)(bsums + 128);        // 1
    unsigned long long* mask1 = (unsigned long long*)(((uintptr_t)(c_total + 1) + 7) & ~(uintptr_t)7);
    unsigned long long* mask2 = mask1 + NMASKW;
    // CSR-build scratch aliases (dead regions during build)
    int*   H      = (int*)ybuf;                   // NBKT*P_SORT
    int*   Hs     = H + HLEN;                     // NBKT*P_SORT
    int2*  ebuf   = (int2*)zbuf;                  // E pairs (12.8 MB <= 25.6 MB region)
    __half* yh    = (__half*)ybuf;                // fp16 y for GIN2/3

    const int nblk_n   = (NN + 255) / 256;
    const int nblk_n16 = NN / 16;

    // CSR by dst: coarse hist (+graph offs) -> scan -> pair scatter -> per-bucket LDS CSR
    k_hist_coarse<<<P_SORT, 256, 0, stream>>>(dst, batch, offs, H);
    k_iscan_blk<<<HSCAN_BLK, 256, 0, stream>>>(H, Hs, bsums, HLEN);
    k_iscan_add<<<(HLEN + 255) / 256, 256, 0, stream>>>(Hs, bsums, HLEN);
    k_scatter_pairs<<<P_SORT, 256, 0, stream>>>(src, dst, Hs, ebuf);
    k_bucket_csr<<<NBKT, 256, 0, stream>>>(ebuf, Hs, roffs, csrc);

    // ---- GIN1: pre-GEMM (fp32) + gather (fp32, +relu/bias) + post + pool1 ----
    k_pre1_g<<<GVB, 256, 0, stream>>>(x, W11, ybuf);
    k_gather_y<<<nblk_n16, 256, 0, stream>>>(ybuf, roffs, csrc, b11, zbuf);
    k_post_g<<<GVB, 256, 0, stream>>>(zbuf, W12, b12, gW1, roffs, nullptr, nullptr,
                                      hA, hwd, dinv, 1);
    k_pool<<<NB, 256, 0, stream>>>(roffs, csrc, hwd, dinv, gb1, nullptr, offs,
                                   score1, keep1, sk1);
    k_pack<<<nblk_n, 256, 0, stream>>>(keep1, mask1);

    // ---- GIN2 (fp16 gather payload, bitmask gate/count) + pool2 ----
    k_pre23_h<<<GVB, 256, 0, stream>>>(hA, sk1, W21, yh);
    k_gather_h<<<nblk_n16, 256, 0, stream>>>(yh, roffs, csrc, mask1, b21, zbuf, cnt);
    k_post_g<<<GVB, 256, 0, stream>>>(zbuf, W22, b22, gW2, roffs, cnt, keep1,
                                      hB, hwd, dinv, 2);
    k_pool<<<NB, 256, 0, stream>>>(roffs, csrc, hwd, dinv, gb2, keep1, offs,
                                   score2, keep2, sk2);
    k_pack<<<nblk_n, 256, 0, stream>>>(keep2, mask2);

    // ---- GIN3 (fp16 gather payload; h3 written into hA buffer) ----
    k_pre23_h<<<GVB, 256, 0, stream>>>(hB, sk2, W31, yh);
    k_gather_h<<<nblk_n16, 256, 0, stream>>>(yh, roffs, csrc, mask2, b31, zbuf, nullptr);
    k_post_g<<<GVB, 256, 0, stream>>>(zbuf, W32, b32, nullptr, roffs, nullptr, nullptr,
                                      hA, nullptr, nullptr, 3);

    // ---- prefix sum of keep1 ----
    k_scan1<<<NSCAN_BLK, 256, 0, stream>>>(keep1, prefix, bsums);
    k_scan3<<<nblk_n, 256, 0, stream>>>(prefix, bsums);

    // ---- fused tail: gmax+linear+KL, then ratio ----
    hipMemsetAsync(c_total, 0, sizeof(float), stream);
    k_tail<<<NB, 256, 0, stream>>>(hA, keep2, offs, Wl, bl, score2, prefix, natt,
                                   out, out + NB, c_total);
    k_final<<<1, 1, 0, stream>>>(c_total, out + 2 * NB);
}

// Round 15
// 502.112 us; speedup vs baseline: 1.1899x; 1.0118x over previous
//
#include <hip/hip_runtime.h>
#include <hip/hip_fp16.h>
#include <math.h>

#define NN 100000
#define NE 1600000
#define NB 256
#define NEGF (-1e30f)
#define GVB 1024            // grid-stride GEMV blocks
#define P_SORT 256          // blocks in coarse histogram/scatter
#define NBKT 391            // ceil(NN/256) coarse buckets (dst>>8)
#define HLEN (NBKT * P_SORT)
#define HSCAN_BLK ((HLEN + 1023) / 1024)
#define BKT_CAP 6144        // LDS staging ints (24 KB); avg bucket = 4096 edges
#define NMASKW 1566         // ull words for 100k keep bits

// ---------------- CSR build: two-level counting sort ----------------
__global__ void k_hist_coarse(const int* __restrict__ dst, const int* __restrict__ batch,
                              int* __restrict__ offs, int* __restrict__ H) {
    __shared__ int lh[NBKT];
    int p = blockIdx.x, tid = threadIdx.x;
    if (p == 0) {
        for (int g = tid; g <= NB; g += 256) {
            int lo = 0, hi = NN;
            while (lo < hi) { int mid = (lo + hi) >> 1; if (batch[mid] < g) lo = mid + 1; else hi = mid; }
            offs[g] = lo;
        }
    }
    for (int i = tid; i < NBKT; i += 256) lh[i] = 0;
    __syncthreads();
    int c0 = p * (NE / P_SORT), c1 = c0 + NE / P_SORT;
    for (int i = c0 + tid; i < c1; i += 256) atomicAdd(&lh[dst[i] >> 8], 1);
    __syncthreads();
    for (int i = tid; i < NBKT; i += 256) H[i * P_SORT + p] = lh[i];
}
__global__ void k_iscan_blk(const int* __restrict__ in, int* __restrict__ pref,
                            int* __restrict__ bsums, int len) {
    int blk = blockIdx.x, tid = threadIdx.x;
    int base = blk * 1024;
    int vals[4], tsum = 0;
    for (int j = 0; j < 4; ++j) {
        int idx = base + tid * 4 + j;
        int v = (idx < len) ? in[idx] : 0;
        vals[j] = tsum; tsum += v;               // exclusive within thread
    }
    __shared__ int sh[256];
    sh[tid] = tsum; __syncthreads();
    for (int o = 1; o < 256; o <<= 1) {
        int v = (tid >= o) ? sh[tid - o] : 0;
        __syncthreads();
        sh[tid] += v;
        __syncthreads();
    }
    int excl = sh[tid] - tsum;
    for (int j = 0; j < 4; ++j) {
        int idx = base + tid * 4 + j;
        if (idx < len) pref[idx] = excl + vals[j];
    }
    if (tid == 255) bsums[blk] = sh[255];
}
__global__ void k_iscan_add(int* __restrict__ pref, const int* __restrict__ bsums, int len) {
    __shared__ int sh[256];
    int t = threadIdx.x;
    int sb = blockIdx.x >> 2;                     // 1024-elem scan-block index
    sh[t] = (t < sb) ? bsums[t] : 0;
    __syncthreads();
    for (int o = 128; o > 0; o >>= 1) { if (t < o) sh[t] += sh[t + o]; __syncthreads(); }
    int pre = sh[0];
    int idx = blockIdx.x * 256 + t;
    if (idx < len) pref[idx] += pre;
}
// packed scatter: word = src | ((dst&255)<<17)  (NN < 2^17)
__global__ void k_scatter_pairs(const int* __restrict__ src, const int* __restrict__ dst,
                                const int* __restrict__ Hs, int* __restrict__ ebuf) {
    __shared__ int curs[NBKT];
    int p = blockIdx.x, tid = threadIdx.x;
    for (int i = tid; i < NBKT; i += 256) curs[i] = Hs[i * P_SORT + p];
    __syncthreads();
    int c0 = p * (NE / P_SORT), c1 = c0 + NE / P_SORT;
    for (int i = c0 + tid; i < c1; i += 256) {
        int d = dst[i];
        int pos = atomicAdd(&curs[d >> 8], 1);
        ebuf[pos] = src[i] | ((d & 255) << 17);
    }
}
__global__ void k_bucket_csr(const int* __restrict__ ebuf, const int* __restrict__ Hs,
                             int* __restrict__ roffs, int* __restrict__ csrc) {
    __shared__ int hist2[256];
    __shared__ int curs2[256];
    __shared__ int sh[256];
    __shared__ int stage[BKT_CAP];
    int b = blockIdx.x, tid = threadIdx.x;
    int e0 = Hs[b * P_SORT];
    int e1 = (b + 1 < NBKT) ? Hs[(b + 1) * P_SORT] : NE;
    int n0 = b * 256;
    int cntb = e1 - e0;
    if (b == 0 && tid == 0) roffs[NN] = NE;
    hist2[tid] = 0;
    __syncthreads();
    for (int i = e0 + tid; i < e1; i += 256) atomicAdd(&hist2[ebuf[i] >> 17], 1);
    __syncthreads();
    int v = hist2[tid];
    sh[tid] = v; __syncthreads();
    for (int o = 1; o < 256; o <<= 1) {
        int u = (tid >= o) ? sh[tid - o] : 0;
        __syncthreads();
        sh[tid] += u;
        __syncthreads();
    }
    int excl = sh[tid] - v;
    int node = n0 + tid;
    if (node < NN) roffs[node] = e0 + excl;
    curs2[tid] = excl;
    __syncthreads();
    if (cntb <= BKT_CAP) {
        for (int i = e0 + tid; i < e1; i += 256) {
            int pr = ebuf[i];
            int pos = atomicAdd(&curs2[pr >> 17], 1);
            stage[pos] = pr & 0x1FFFF;
        }
        __syncthreads();
        for (int i = tid; i < cntb; i += 256) csrc[e0 + i] = stage[i];
    } else {
        for (int i = e0 + tid; i < e1; i += 256) {
            int pr = ebuf[i];
            int pos = atomicAdd(&curs2[pr >> 17], 1);
            csrc[e0 + pos] = pr & 0x1FFFF;
        }
    }
}

// ---------------- GEMV kernels: W in VGPRs, broadcast via wave-local LDS ds_read_b128 -----
__global__ __launch_bounds__(256) void k_pre1_g(const float* __restrict__ x,
                                                const float* __restrict__ W,
                                                float* __restrict__ y) {
    __shared__ float lds[4][4 * 128];
    int tid = threadIdx.x, w = tid >> 6, l = tid & 63;
    float Wc[128];
#pragma unroll
    for (int k = 0; k < 128; ++k) Wc[k] = W[k * 64 + l];
    float* row = lds[w];
    int g = blockIdx.x * 4 + w;
    const int G = GVB * 4;
    for (int t = g; t < NN / 4; t += G) {
        int n0 = t * 4;
#pragma unroll
        for (int r = 0; r < 4; ++r) {
            row[r * 128 + l]      = x[(size_t)(n0 + r) * 128 + l];
            row[r * 128 + 64 + l] = x[(size_t)(n0 + r) * 128 + 64 + l];
        }
        __builtin_amdgcn_wave_barrier();
        float acc[4] = {0.f, 0.f, 0.f, 0.f};
#pragma unroll
        for (int k = 0; k < 128; k += 4) {
#pragma unroll
            for (int r = 0; r < 4; ++r) {
                float4 bv = *(const float4*)&row[r * 128 + k];   // uniform addr -> LDS broadcast
                acc[r] = fmaf(bv.x, Wc[k],     acc[r]);
                acc[r] = fmaf(bv.y, Wc[k + 1], acc[r]);
                acc[r] = fmaf(bv.z, Wc[k + 2], acc[r]);
                acc[r] = fmaf(bv.w, Wc[k + 3], acc[r]);
            }
        }
        __builtin_amdgcn_wave_barrier();
#pragma unroll
        for (int r = 0; r < 4; ++r) y[(size_t)(n0 + r) * 64 + l] = acc[r];
    }
}

__global__ __launch_bounds__(256) void k_pre23_h(const float* __restrict__ h,
                                                 const float* __restrict__ sk,
                                                 const float* __restrict__ W,
                                                 __half* __restrict__ yh) {
    __shared__ float lds[4][8 * 64];
    int tid = threadIdx.x, w = tid >> 6, l = tid & 63;
    float Wc[64];
#pragma unroll
    for (int k = 0; k < 64; ++k) Wc[k] = W[k * 64 + l];
    float* row = lds[w];
    int g = blockIdx.x * 4 + w;
    const int G = GVB * 4;
    for (int t = g; t < NN / 8; t += G) {
        int n0 = t * 8;
#pragma unroll
        for (int r = 0; r < 8; ++r) row[r * 64 + l] = h[(size_t)(n0 + r) * 64 + l];
        __builtin_amdgcn_wave_barrier();
        float acc[8] = {0.f, 0.f, 0.f, 0.f, 0.f, 0.f, 0.f, 0.f};
#pragma unroll
        for (int k = 0; k < 64; k += 4) {
#pragma unroll
            for (int r = 0; r < 8; ++r) {
                float4 bv = *(const float4*)&row[r * 64 + k];
                acc[r] = fmaf(bv.x, Wc[k],     acc[r]);
                acc[r] = fmaf(bv.y, Wc[k + 1], acc[r]);
                acc[r] = fmaf(bv.z, Wc[k + 2], acc[r]);
                acc[r] = fmaf(bv.w, Wc[k + 3], acc[r]);
            }
        }
        __builtin_amdgcn_wave_barrier();
#pragma unroll
        for (int r = 0; r < 8; ++r)
            yh[(size_t)(n0 + r) * 64 + l] = __float2half(acc[r] * sk[n0 + r]);
    }
}

__global__ __launch_bounds__(256) void k_post_g(const float* __restrict__ zp,
                                                const float* __restrict__ W2,
                                                const float* __restrict__ b2,
                                                const float* __restrict__ gW,
                                                const int* __restrict__ roffs,
                                                const int* __restrict__ cnt,
                                                const float* __restrict__ keep,
                                                float* __restrict__ hOut,
                                                float* __restrict__ hwd,
                                                float* __restrict__ dinv, int mode) {
    __shared__ float lds[4][8 * 64];
    int tid = threadIdx.x, w = tid >> 6, l = tid & 63;
    float Wc[64];
#pragma unroll
    for (int k = 0; k < 64; ++k) Wc[k] = W2[k * 64 + l];
    float b2v = b2[l];
    float gWv = (mode < 3) ? gW[l] : 0.f;
    float* row = lds[w];
    int g = blockIdx.x * 4 + w;
    const int G = GVB * 4;
    for (int t = g; t < NN / 8; t += G) {
        int n0 = t * 8;
#pragma unroll
        for (int r = 0; r < 8; ++r) row[r * 64 + l] = zp[(size_t)(n0 + r) * 64 + l];
        __builtin_amdgcn_wave_barrier();
        float acc[8];
#pragma unroll
        for (int r = 0; r < 8; ++r) acc[r] = b2v;
#pragma unroll
        for (int k = 0; k < 64; k += 4) {
#pragma unroll
            for (int r = 0; r < 8; ++r) {
                float4 bv = *(const float4*)&row[r * 64 + k];
                acc[r] = fmaf(bv.x, Wc[k],     acc[r]);
                acc[r] = fmaf(bv.y, Wc[k + 1], acc[r]);
                acc[r] = fmaf(bv.z, Wc[k + 2], acc[r]);
                acc[r] = fmaf(bv.w, Wc[k + 3], acc[r]);
            }
        }
        __builtin_amdgcn_wave_barrier();
#pragma unroll
        for (int r = 0; r < 8; ++r) {
            acc[r] = fmaxf(acc[r], 0.f);
            hOut[(size_t)(n0 + r) * 64 + l] = acc[r];
        }
        if (mode < 3) {
#pragma unroll
            for (int r = 0; r < 8; ++r) {
                float t2 = acc[r] * gWv;
                for (int o = 32; o > 0; o >>= 1) t2 += __shfl_down(t2, o, 64);
                if (l == 0) {
                    int n = n0 + r;
                    float di;
                    if (mode == 1) di = 1.f / sqrtf((float)(roffs[n + 1] - roffs[n]) + 1.f);
                    else di = (keep[n] != 0.f) ? 1.f / sqrtf((float)cnt[n] + 1.f) : 0.f;
                    dinv[n] = di;
                    hwd[n] = t2 * di;
                }
            }
        }
    }
}

// ---------------- fp32 CSR gather (GIN1): 16 lanes/node, float4, unroll-4 -----------------
__global__ void k_gather_y(const float* __restrict__ y, const int* __restrict__ roffs,
                           const int* __restrict__ csrc, const float* __restrict__ b1,
                           float* __restrict__ z) {
    int tid = threadIdx.x;
    int d = blockIdx.x * 16 + (tid >> 4);
    int l = tid & 15;
    const float4* y4 = (const float4*)y;
    float4 acc = y4[(size_t)d * 16 + l];            // self term
    int e0 = roffs[d], e1 = roffs[d + 1];
    int e = e0;
    for (; e + 3 < e1; e += 4) {
        int s0 = csrc[e], s1 = csrc[e + 1], s2 = csrc[e + 2], s3 = csrc[e + 3];
        float4 v0 = y4[(size_t)s0 * 16 + l];
        float4 v1 = y4[(size_t)s1 * 16 + l];
        float4 v2 = y4[(size_t)s2 * 16 + l];
        float4 v3 = y4[(size_t)s3 * 16 + l];
        acc.x += (v0.x + v1.x) + (v2.x + v3.x);
        acc.y += (v0.y + v1.y) + (v2.y + v3.y);
        acc.z += (v0.z + v1.z) + (v2.z + v3.z);
        acc.w += (v0.w + v1.w) + (v2.w + v3.w);
    }
    for (; e < e1; ++e) {
        float4 v0 = y4[(size_t)csrc[e] * 16 + l];
        acc.x += v0.x; acc.y += v0.y; acc.z += v0.z; acc.w += v0.w;
    }
    float4 o;
    o.x = fmaxf(acc.x + b1[4 * l],     0.f);
    o.y = fmaxf(acc.y + b1[4 * l + 1], 0.f);
    o.z = fmaxf(acc.z + b1[4 * l + 2], 0.f);
    o.w = fmaxf(acc.w + b1[4 * l + 3], 0.f);
    ((float4*)z)[(size_t)d * 16 + l] = o;
}

// ---------------- fp16 CSR gather (GIN2/GIN3): 16 lanes/node; keep-bitmask gate/count -----
__global__ void k_gather_h(const __half* __restrict__ yh, const int* __restrict__ roffs,
                           const int* __restrict__ csrc,
                           const unsigned long long* __restrict__ kmask,
                           const float* __restrict__ b1,
                           float* __restrict__ z, int* __restrict__ cnt) {
    int tid = threadIdx.x;
    int d = blockIdx.x * 16 + (tid >> 4);
    int l = tid & 15;
    const float2* yv = (const float2*)yh;           // 8 B = 4 halves per load
    float2 raw = yv[(size_t)d * 16 + l];
    __half2 p0 = ((const __half2*)&raw)[0], p1 = ((const __half2*)&raw)[1];
    float4 acc = make_float4(__low2float(p0), __high2float(p0),
                             __low2float(p1), __high2float(p1));  // self term
    int c = 0;
    if ((kmask[d >> 6] >> (d & 63)) & 1ull) {       // dst-side gate (group-uniform)
        int e0 = roffs[d], e1 = roffs[d + 1];
        int e = e0;
        for (; e + 3 < e1; e += 4) {
            int s0 = csrc[e], s1 = csrc[e + 1], s2 = csrc[e + 2], s3 = csrc[e + 3];
            float2 r0 = yv[(size_t)s0 * 16 + l];
            float2 r1 = yv[(size_t)s1 * 16 + l];
            float2 r2 = yv[(size_t)s2 * 16 + l];
            float2 r3 = yv[(size_t)s3 * 16 + l];
#pragma unroll
            for (int j = 0; j < 4; ++j) {
                float2 rr = (j == 0) ? r0 : (j == 1) ? r1 : (j == 2) ? r2 : r3;
                __half2 a0 = ((const __half2*)&rr)[0], a1 = ((const __half2*)&rr)[1];
                acc.x += __low2float(a0); acc.y += __high2float(a0);
                acc.z += __low2float(a1); acc.w += __high2float(a1);
            }
            if (cnt) c += (int)((kmask[s0 >> 6] >> (s0 & 63)) & 1ull)
                        + (int)((kmask[s1 >> 6] >> (s1 & 63)) & 1ull)
                        + (int)((kmask[s2 >> 6] >> (s2 & 63)) & 1ull)
                        + (int)((kmask[s3 >> 6] >> (s3 & 63)) & 1ull);
        }
        for (; e < e1; ++e) {
            int s0 = csrc[e];
            float2 rr = yv[(size_t)s0 * 16 + l];
            __half2 a0 = ((const __half2*)&rr)[0], a1 = ((const __half2*)&rr)[1];
            acc.x += __low2float(a0); acc.y += __high2float(a0);
            acc.z += __low2float(a1); acc.w += __high2float(a1);
            if (cnt) c += (int)((kmask[s0 >> 6] >> (s0 & 63)) & 1ull);
        }
    }
    float4 o;
    o.x = fmaxf(acc.x + b1[4 * l],     0.f);
    o.y = fmaxf(acc.y + b1[4 * l + 1], 0.f);
    o.z = fmaxf(acc.z + b1[4 * l + 2], 0.f);
    o.w = fmaxf(acc.w + b1[4 * l + 3], 0.f);
    ((float4*)z)[(size_t)d * 16 + l] = o;
    if (cnt && l == 0) cnt[d] = c;
}

// ---------------- fused pool (512 thr): per-graph attn (LDS) + softmax + threshold + sk ---
__global__ __launch_bounds__(512) void k_pool(const int* __restrict__ roffs,
                       const int* __restrict__ csrc,
                       const float* __restrict__ hwd, const float* __restrict__ dinv,
                       const float* __restrict__ gb, const float* __restrict__ nmask,
                       const int* __restrict__ offs, float* __restrict__ score,
                       float* __restrict__ keep, float* __restrict__ sk) {
    __shared__ float attn_s[2048];
    __shared__ float red[512];
    int b = blockIdx.x, tid = threadIdx.x;
    int s0 = offs[b], s1 = offs[b + 1];
    int len = s1 - s0;
    float gbv = gb[0];
    for (int j = tid; j < len; j += 512) {
        int i = s0 + j;
        float a = NEGF;
        if (!nmask || nmask[i] > 0.f) {             // skip edge work for dropped nodes
            float sum = hwd[i];
            int e0 = roffs[i], e1 = roffs[i + 1];
            for (int e = e0; e < e1; ++e) sum += hwd[csrc[e]];
            a = dinv[i] * sum + gbv;
        }
        attn_s[j] = a;
    }
    __syncthreads();
    float m = NEGF;
    for (int j = tid; j < len; j += 512) m = fmaxf(m, attn_s[j]);
    red[tid] = m; __syncthreads();
    for (int o = 256; o > 0; o >>= 1) { if (tid < o) red[tid] = fmaxf(red[tid], red[tid + o]); __syncthreads(); }
    m = red[0]; __syncthreads();
    float s = 0.f;
    for (int j = tid; j < len; j += 512) {
        float a = attn_s[j];
        if (a > 0.5f * NEGF) s += expf(a - m);
    }
    red[tid] = s; __syncthreads();
    for (int o = 256; o > 0; o >>= 1) { if (tid < o) red[tid] += red[tid + o]; __syncthreads(); }
    s = red[0]; __syncthreads();
    float sden = fmaxf(s, 1e-30f);
    float smax = NEGF;
    for (int j = tid; j < len; j += 512) {
        float a = attn_s[j];
        float sc = (a > 0.5f * NEGF) ? expf(a - m) / sden : 0.f;
        score[s0 + j] = sc;
        attn_s[j] = sc;                              // reuse LDS: now holds scores
        smax = fmaxf(smax, (a > 0.5f * NEGF) ? sc : NEGF);
    }
    red[tid] = smax; __syncthreads();
    for (int o = 256; o > 0; o >>= 1) { if (tid < o) red[tid] = fmaxf(red[tid], red[tid + o]); __syncthreads(); }
    smax = red[0]; __syncthreads();
    float thr = fminf(1e-3f, smax - 1e-7f);          // thr > 0, so dropped (sc=0) never pass
    for (int j = tid; j < len; j += 512) {
        float sc = attn_s[j];
        float kp = (sc > thr) ? 1.f : 0.f;
        keep[s0 + j] = kp;
        sk[s0 + j] = sc * kp;
    }
}

// ---------------- pack keep -> bitmask via ballot ----------------
__global__ void k_pack(const float* __restrict__ keep, unsigned long long* __restrict__ mask) {
    int i = blockIdx.x * 256 + threadIdx.x;
    float v = (i < NN) ? keep[i] : 0.f;
    unsigned long long m = __ballot(v > 0.f);
    if ((threadIdx.x & 63) == 0) mask[(unsigned)i >> 6] = m;
}

// ---------------- word-prefix popcount table over mask1 ----------------
__global__ void k_wpref(const unsigned long long* __restrict__ mask, int* __restrict__ wpref) {
    __shared__ int sh[256];
    int t = threadIdx.x;
    int base = t * 7;
    int cnts[7]; int tsum = 0;
#pragma unroll
    for (int j = 0; j < 7; ++j) {
        int w = base + j;
        cnts[j] = tsum;
        if (w < NMASKW) tsum += (int)__popcll(mask[w]);
    }
    sh[t] = tsum; __syncthreads();
    for (int o = 1; o < 256; o <<= 1) {
        int v = (t >= o) ? sh[t - o] : 0;
        __syncthreads(); sh[t] += v; __syncthreads();
    }
    int excl = sh[t] - tsum;
#pragma unroll
    for (int j = 0; j < 7; ++j) {
        int w = base + j;
        if (w < NMASKW) wpref[w] = excl + cnts[j];
    }
}

// ---------------- fused tail: gmax+linear + KL + (last block) ratio ----------------
__global__ void k_tail(const float* __restrict__ h, const float* __restrict__ keep2,
                       const int* __restrict__ offs, const float* __restrict__ Wl,
                       const float* __restrict__ bl, const float* __restrict__ score2,
                       const unsigned long long* __restrict__ mask1,
                       const int* __restrict__ wpref, const float* __restrict__ natt,
                       float* __restrict__ out, float* __restrict__ out_loss,
                       float* __restrict__ c_total, int* __restrict__ done) {
    int b = blockIdx.x, tid = threadIdx.x;
    int s0 = offs[b], s1 = offs[b + 1];
    int f = tid & 63, g = tid >> 6;
    float m = NEGF;
    for (int i = s0 + g; i < s1; i += 4)
        if (keep2[i] > 0.f) m = fmaxf(m, h[(size_t)i * 64 + f]);
    __shared__ float red[256];
    red[tid] = m; __syncthreads();
    if (g == 0) {
        m = fmaxf(fmaxf(red[f], red[64 + f]), fmaxf(red[128 + f], red[192 + f]));
        float v = m * Wl[f];
        for (int o = 32; o > 0; o >>= 1) v += __shfl_down(v, o, 64);
        if (f == 0) out[b] = v + bl[0];
    }
    __syncthreads();
    float ssum = 0.f, c = 0.f;
    for (int i = s0 + tid; i < s1; i += 256) {
        if (keep2[i] > 0.f) {
            int w = i >> 6, bb = i & 63;
            int r1 = wpref[w] + (int)__popcll(mask1[w] & ((1ull << bb) - 1ull));
            r1 = max(0, min(r1, NN - 1));
            float t = natt[r1];
            float logp = logf(score2[i] + 1e-14f);
            float kl = ((t > 0.f) ? t * logf(fmaxf(t, 1e-38f)) : 0.f) - t * logp;
            ssum += kl; c += 1.f;
        }
    }
    __shared__ float rs[256], rc[256];
    rs[tid] = ssum; rc[tid] = c; __syncthreads();
    for (int o = 128; o > 0; o >>= 1) {
        if (tid < o) { rs[tid] += rs[tid + o]; rc[tid] += rc[tid + o]; }
        __syncthreads();
    }
    if (tid == 0) {
        out_loss[b] = rs[0] / fmaxf(rc[0], 1.f);
        atomicAdd(c_total, rc[0]);
        __threadfence();
        int t = atomicAdd(done, 1);
        if (t == NB - 1) out[2 * NB] = *(volatile float*)c_total / (float)NN;
    }
}

extern "C" void kernel_launch(void* const* d_in, const int* in_sizes, int n_in,
                              void* d_out, int out_size, void* d_ws, size_t ws_size,
                              hipStream_t stream) {
    const float* x    = (const float*)d_in[0];
    const int*   src  = (const int*)d_in[1];
    const int*   dst  = (const int*)d_in[2];
    const int*   batch= (const int*)d_in[3];
    const float* natt = (const float*)d_in[4];
    const float* W11 = (const float*)d_in[5],  *b11 = (const float*)d_in[6];
    const float* W12 = (const float*)d_in[7],  *b12 = (const float*)d_in[8];
    const float* gW1 = (const float*)d_in[9],  *gb1 = (const float*)d_in[10];
    const float* W21 = (const float*)d_in[11], *b21 = (const float*)d_in[12];
    const float* W22 = (const float*)d_in[13], *b22 = (const float*)d_in[14];
    const float* gW2 = (const float*)d_in[15], *gb2 = (const float*)d_in[16];
    const float* W31 = (const float*)d_in[17], *b31 = (const float*)d_in[18];
    const float* W32 = (const float*)d_in[19], *b32 = (const float*)d_in[20];
    const float* Wl  = (const float*)d_in[21], *bl  = (const float*)d_in[22];
    float* out = (float*)d_out;

    // workspace layout
    float* hA     = (float*)d_ws;                 // N*64  (reused as h3)
    float* hB     = hA + (size_t)NN * 64;         // N*64
    float* ybuf   = hB + (size_t)NN * 64;         // N*64  (CSR build: H/Hs; fp16 y aliases)
    float* zbuf   = ybuf + (size_t)NN * 64;       // N*64  (CSR build: ebuf aliases)
    float* hwd    = zbuf + (size_t)NN * 64;       // N
    float* dinv   = hwd + NN;                     // N
    float* score1 = dinv + NN;                    // N
    float* keep1  = score1 + NN;                  // N
    float* sk1    = keep1 + NN;                   // N
    float* score2 = sk1 + NN;                     // N
    float* keep2  = score2 + NN;                  // N
    float* sk2    = keep2 + NN;                   // N
    int*   wpref  = (int*)(sk2 + NN);             // NMASKW
    int*   cnt    = wpref + NMASKW;               // N
    int*   roffs  = cnt + NN;                     // N+1
    int*   csrc   = roffs + NN + 1;               // E
    int*   offs   = csrc + NE;                    // B+1
    int*   bsums  = offs + NB + 1;                // 128
    float* c_total= (float*)(bsums + 128);        // 1
    int*   done   = (int*)(c_total + 1);          // 1
    unsigned long long* mask1 = (unsigned long long*)(((uintptr_t)(done + 1) + 7) & ~(uintptr_t)7);
    unsigned long long* mask2 = mask1 + NMASKW;
    // CSR-build scratch aliases (dead regions during build)
    int*   H      = (int*)ybuf;                   // NBKT*P_SORT
    int*   Hs     = H + HLEN;                     // NBKT*P_SORT
    int*   ebuf   = (int*)zbuf;                   // E packed words (6.4 MB <= 25.6 MB region)
    __half* yh    = (__half*)ybuf;                // fp16 y for GIN2/3

    const int nblk_n   = (NN + 255) / 256;
    const int nblk_n16 = NN / 16;

    // CSR by dst: coarse hist (+graph offs) -> scan -> packed scatter -> per-bucket LDS CSR
    k_hist_coarse<<<P_SORT, 256, 0, stream>>>(dst, batch, offs, H);
    k_iscan_blk<<<HSCAN_BLK, 256, 0, stream>>>(H, Hs, bsums, HLEN);
    k_iscan_add<<<(HLEN + 255) / 256, 256, 0, stream>>>(Hs, bsums, HLEN);
    k_scatter_pairs<<<P_SORT, 256, 0, stream>>>(src, dst, Hs, ebuf);
    k_bucket_csr<<<NBKT, 256, 0, stream>>>(ebuf, Hs, roffs, csrc);

    // ---- GIN1: pre-GEMM (fp32) + gather (fp32, +relu/bias) + post + pool1 ----
    k_pre1_g<<<GVB, 256, 0, stream>>>(x, W11, ybuf);
    k_gather_y<<<nblk_n16, 256, 0, stream>>>(ybuf, roffs, csrc, b11, zbuf);
    k_post_g<<<GVB, 256, 0, stream>>>(zbuf, W12, b12, gW1, roffs, nullptr, nullptr,
                                      hA, hwd, dinv, 1);
    k_pool<<<NB, 512, 0, stream>>>(roffs, csrc, hwd, dinv, gb1, nullptr, offs,
                                   score1, keep1, sk1);
    k_pack<<<nblk_n, 256, 0, stream>>>(keep1, mask1);
    k_wpref<<<1, 256, 0, stream>>>(mask1, wpref);

    // ---- GIN2 (fp16 gather payload, bitmask gate/count) + pool2 ----
    k_pre23_h<<<GVB, 256, 0, stream>>>(hA, sk1, W21, yh);
    k_gather_h<<<nblk_n16, 256, 0, stream>>>(yh, roffs, csrc, mask1, b21, zbuf, cnt);
    k_post_g<<<GVB, 256, 0, stream>>>(zbuf, W22, b22, gW2, roffs, cnt, keep1,
                                      hB, hwd, dinv, 2);
    k_pool<<<NB, 512, 0, stream>>>(roffs, csrc, hwd, dinv, gb2, keep1, offs,
                                   score2, keep2, sk2);
    k_pack<<<nblk_n, 256, 0, stream>>>(keep2, mask2);

    // ---- GIN3 (fp16 gather payload; h3 written into hA buffer) ----
    k_pre23_h<<<GVB, 256, 0, stream>>>(hB, sk2, W31, yh);
    k_gather_h<<<nblk_n16, 256, 0, stream>>>(yh, roffs, csrc, mask2, b31, zbuf, nullptr);
    k_post_g<<<GVB, 256, 0, stream>>>(zbuf, W32, b32, nullptr, roffs, nullptr, nullptr,
                                      hA, nullptr, nullptr, 3);

    // ---- fused tail: gmax+linear+KL+ratio ----
    hipMemsetAsync(c_total, 0, sizeof(float) + sizeof(int), stream);
    k_tail<<<NB, 256, 0, stream>>>(hA, keep2, offs, Wl, bl, score2, mask1, wpref, natt,
                                   out, out + NB, c_total, done);
}